// Round 1
// baseline (6796.532 us; speedup 1.0000x reference)
//
#include <hip/hip_runtime.h>
#include <math.h>

#define B_ 1024
#define E_ 6
#define CAPF 192.0f

// ---------------------------------------------------------------------------
// Weight prep: fold BN (scale s = g/sqrt(1+eps)) into conv weights and bias,
// transpose weights [E][CO][CI][3][3] -> [E][CI][3][3][CO] (co contiguous so
// the conv inner loop does wave-uniform scalar loads).
// ---------------------------------------------------------------------------
__global__ void prep_w(const float* __restrict__ w, const float* __restrict__ g,
                       float* __restrict__ wout, int CO, int CI, int total) {
    int i = blockIdx.x * 256 + threadIdx.x;
    if (i >= total) return;
    int k = i % 9;
    int t = i / 9;
    int ci = t % CI; t /= CI;
    int co = t % CO;
    int e  = t / CO;
    float s = g[e * CO + co] * (1.0f / sqrtf(1.0f + 1e-5f));
    wout[(((long)(e * CI + ci) * 9 + k) * CO) + co] = w[i] * s;
}

__global__ void prep_b(const float* __restrict__ cb, const float* __restrict__ g,
                       const float* __restrict__ bb, float* __restrict__ bout, int N) {
    int i = blockIdx.x * 256 + threadIdx.x;
    if (i >= N) return;
    float s = g[i] * (1.0f / sqrtf(1.0f + 1e-5f));
    float c = (cb != nullptr) ? cb[i] : 0.0f;
    bout[i] = c * s + bb[i];
}

// ---------------------------------------------------------------------------
// Direct 3x3 conv (pad=1) + folded-BN bias + ReLU (+ optional fused 2x2 maxpool).
// Block = 256 threads handles one TSxTS conv tile of one image.
// Thread = one output pixel (or one pooled pixel = 2x2 conv pixels),
// accumulating COT output channels in registers. Weights streamed as
// wave-uniform scalar loads (co-contiguous layout).
// ---------------------------------------------------------------------------
template <int CI, int CO, int H, int TS, int CO_BLK, int CI_CHUNK, bool POOL>
__launch_bounds__(256)
__global__ void conv3x3(const float* __restrict__ in, const float* __restrict__ wt,
                        const float* __restrict__ bias, float* __restrict__ out) {
    constexpr int TD = H / TS;
    constexpr int TILES = TD * TD;
    constexpr int LW = TS + 2;
    constexpr int NPX = POOL ? (TS / 2) * (TS / 2) : TS * TS;
    constexpr int G = 256 / NPX;          // co groups handled in parallel by threads
    constexpr int NG = CO / CO_BLK;       // total co groups
    constexpr int GPT = NG / G;           // groups per thread (serial)
    constexpr int COT = GPT * CO_BLK;     // co per thread
    constexpr int NW = POOL ? 4 : 1;      // conv px per thread
    constexpr int OD = POOL ? TS / 2 : TS;

    __shared__ float lds[CI_CHUNK * LW * LW];

    int bid = blockIdx.x;
    int n = bid / TILES;
    int t = bid % TILES;
    int ty = (t / TD) * TS;
    int tx = (t % TD) * TS;
    int tid = threadIdx.x;
    int px = tid % NPX;
    int cg0 = tid / NPX;                      // wave-uniform by construction
    const int cg0s = __builtin_amdgcn_readfirstlane(cg0);
    int oy = px / OD;
    int ox = px % OD;

    float acc[NW][COT];
#pragma unroll
    for (int g2 = 0; g2 < GPT; ++g2)
#pragma unroll
        for (int j = 0; j < CO_BLK; ++j) {
            float bv = bias[(cg0s + g2 * G) * CO_BLK + j];
#pragma unroll
            for (int p = 0; p < NW; ++p) acc[p][g2 * CO_BLK + j] = bv;
        }

    for (int cc = 0; cc < CI / CI_CHUNK; ++cc) {
        const float* inb = in + ((long)n * CI + cc * CI_CHUNK) * (H * H);
        for (int idx = tid; idx < CI_CHUNK * LW * LW; idx += 256) {
            int ci = idx / (LW * LW);
            int r = idx - ci * (LW * LW);
            int yy = r / LW + ty - 1;
            int xx = r % LW + tx - 1;
            float v = 0.0f;
            if ((unsigned)yy < (unsigned)H && (unsigned)xx < (unsigned)H)
                v = inb[ci * H * H + yy * H + xx];
            lds[idx] = v;
        }
        __syncthreads();

        const float* wbase = wt + ((long)cc * CI_CHUNK) * 9 * CO;
        for (int ci = 0; ci < CI_CHUNK; ++ci) {
#pragma unroll
            for (int ky = 0; ky < 3; ++ky) {
#pragma unroll
                for (int kx = 0; kx < 3; ++kx) {
                    float v[NW];
                    if constexpr (POOL) {
#pragma unroll
                        for (int dy = 0; dy < 2; ++dy)
#pragma unroll
                            for (int dx = 0; dx < 2; ++dx)
                                v[dy * 2 + dx] =
                                    lds[ci * LW * LW + (2 * oy + dy + ky) * LW + (2 * ox + dx + kx)];
                    } else {
                        v[0] = lds[ci * LW * LW + (oy + ky) * LW + (ox + kx)];
                    }
                    const float* wr = wbase + ((ci * 3 + ky) * 3 + kx) * CO + cg0s * CO_BLK;
#pragma unroll
                    for (int g2 = 0; g2 < GPT; ++g2)
#pragma unroll
                        for (int j = 0; j < CO_BLK; ++j) {
                            float wv = wr[g2 * G * CO_BLK + j];
#pragma unroll
                            for (int p = 0; p < NW; ++p)
                                acc[p][g2 * CO_BLK + j] = fmaf(v[p], wv, acc[p][g2 * CO_BLK + j]);
                        }
                }
            }
        }
        __syncthreads();
    }

    if constexpr (POOL) {
        constexpr int HP = H / 2;
        int py = ty / 2 + oy;
        int pxx = tx / 2 + ox;
#pragma unroll
        for (int g2 = 0; g2 < GPT; ++g2)
#pragma unroll
            for (int j = 0; j < CO_BLK; ++j) {
                int co = (cg0s + g2 * G) * CO_BLK + j;
                int a = g2 * CO_BLK + j;
                float m = fmaxf(fmaxf(acc[0][a], acc[1][a]), fmaxf(acc[2][a], acc[3][a]));
                out[((long)n * CO + co) * (HP * HP) + py * HP + pxx] = fmaxf(m, 0.0f);
            }
    } else {
        int yy = ty + oy;
        int xx = tx + ox;
#pragma unroll
        for (int g2 = 0; g2 < GPT; ++g2)
#pragma unroll
            for (int j = 0; j < CO_BLK; ++j) {
                int co = (cg0s + g2 * G) * CO_BLK + j;
                out[((long)n * CO + co) * (H * H) + yy * H + xx] =
                    fmaxf(acc[0][g2 * CO_BLK + j], 0.0f);
            }
    }
}

// ---------------------------------------------------------------------------
// Trunk pooling: [B,32,16,16] -> maxpool was fused; here avgpool 16x16 -> 2x2
// out[n, c*4 + i*2 + j] = mean over 8x8 block (i,j)
// ---------------------------------------------------------------------------
__global__ void trunk_pool(const float* __restrict__ in, float* __restrict__ out) {
    int g = blockIdx.x * 256 + threadIdx.x;
    if (g >= B_ * 128) return;
    int n = g >> 7;
    int r = g & 127;
    int c = r >> 2;
    int i = (r >> 1) & 1;
    int j = r & 1;
    const float* p = in + ((long)n * 32 + c) * 256 + i * 8 * 16 + j * 8;
    float s = 0.0f;
#pragma unroll
    for (int y = 0; y < 8; ++y)
#pragma unroll
        for (int x = 0; x < 8; ++x) s += p[y * 16 + x];
    out[g] = s * (1.0f / 64.0f);
}

// Global average pool: in [B, C, S] -> out [B, C]
__global__ void gap_k(const float* __restrict__ in, float* __restrict__ out, int C, int S) {
    int g = blockIdx.x * 256 + threadIdx.x;
    if (g >= B_ * C) return;
    const float* p = in + (long)g * S;
    float s = 0.0f;
    for (int k = 0; k < S; ++k) s += p[k];
    out[g] = s / (float)S;
}

// FC: out[n,o] = (relu)( in[n,:] . W[o,:] + b[o] ),  W row-major [O][I]
template <int I, int O, bool RELU>
__global__ void fc_k(const float* __restrict__ in, const float* __restrict__ W,
                     const float* __restrict__ bias, float* __restrict__ out) {
    int g = blockIdx.x * 256 + threadIdx.x;
    if (g >= B_ * O) return;
    int n = g / O;
    int o = g - n * O;
    const float* ip = in + (long)n * I;
    const float* wp = W + (long)o * I;
    float a = bias[o];
#pragma unroll 8
    for (int k = 0; k < I; ++k) a = fmaf(ip[k], wp[k], a);
    if (RELU) a = fmaxf(a, 0.0f);
    out[g] = a;
}

// conf = sum p*log(p+1e-12) from log_softmax of logits; then balanced score.
__global__ void conf_bal_k(const float* __restrict__ logitsE, const float* __restrict__ gate,
                           const float* __restrict__ ema, float* __restrict__ balanced) {
    int g = blockIdx.x * 256 + threadIdx.x;
    if (g >= B_ * E_) return;
    int b = g / E_;
    int e = g - b * E_;
    const float* lp = logitsE + ((long)e * B_ + b) * 10;
    float m = lp[0];
#pragma unroll
    for (int k = 1; k < 10; ++k) m = fmaxf(m, lp[k]);
    float s = 0.0f;
#pragma unroll
    for (int k = 0; k < 10; ++k) s += expf(lp[k] - m);
    float ls = m + logf(s);
    float conf = 0.0f;
#pragma unroll
    for (int k = 0; k < 10; ++k) {
        float p = expf(lp[k] - ls);
        conf += p * logf(p + 1e-12f);
    }
    float em = ema[e];
    float boost = (em < 0.05f) ? (0.05f - em) * 10.0f : 0.0f;
    float comb = 0.7f * (gate[b * E_ + e] / 1.0f) + 0.3f * conf + boost;
    balanced[g] = comb - 2.0f * em;
}

__device__ __forceinline__ float load_sel(int i, float l0, float l1, float l2, float l3,
                                          float l4, float l5) {
    float r = l0;
    r = (i == 1) ? l1 : r;
    r = (i == 2) ? l2 : r;
    r = (i == 3) ? l3 : r;
    r = (i == 4) ? l4 : r;
    r = (i == 5) ? l5 : r;
    return r;
}

// Sequential greedy capacity-constrained dispatch. Single wave (64 lanes).
// Phase 1: each lane computes top-2 experts for its 16 samples (ties: lowest idx).
// Phase 2: sequential over all 1024 samples; state (loads) kept redundantly in
// every lane; candidate indices broadcast with __shfl. Exactly replicates
// argmax(fits) / idxs[argmin(l)] / where(any,...) / loads.at[chosen].add(1).
__global__ void dispatch_k(const float* __restrict__ balanced, int* __restrict__ chosen) {
    int lane = threadIdx.x;
    int t0[16], t1[16], ch[16];
#pragma unroll
    for (int r = 0; r < 16; ++r) {
        int b = r * 64 + lane;
        const float* bp = balanced + b * E_;
        float v[E_];
#pragma unroll
        for (int e = 0; e < E_; ++e) v[e] = bp[e];
        int i0 = 0;
        float m0 = v[0];
#pragma unroll
        for (int e = 1; e < E_; ++e)
            if (v[e] > m0) { m0 = v[e]; i0 = e; }
        int i1 = -1;
        float m1 = -1e38f;
#pragma unroll
        for (int e = 0; e < E_; ++e)
            if (e != i0 && v[e] > m1) { m1 = v[e]; i1 = e; }
        t0[r] = i0;
        t1[r] = i1;
    }
    float l0 = 0, l1 = 0, l2 = 0, l3 = 0, l4 = 0, l5 = 0;
#pragma unroll
    for (int r = 0; r < 16; ++r) {
        for (int q = 0; q < 64; ++q) {
            int i0 = __shfl(t0[r], q);
            int i1 = __shfl(t1[r], q);
            float a0 = load_sel(i0, l0, l1, l2, l3, l4, l5);
            float a1 = load_sel(i1, l0, l1, l2, l3, l4, l5);
            bool f0 = a0 < CAPF;
            bool f1 = a1 < CAPF;
            int fb = (a1 < a0) ? i1 : i0;      // argmin, first on tie
            int c = f0 ? i0 : (f1 ? i1 : fb);  // argmax(fits), first True; 0 if none -> fb
            if (lane == q) ch[r] = c;
            l0 += (c == 0) ? 1.0f : 0.0f;
            l1 += (c == 1) ? 1.0f : 0.0f;
            l2 += (c == 2) ? 1.0f : 0.0f;
            l3 += (c == 3) ? 1.0f : 0.0f;
            l4 += (c == 4) ? 1.0f : 0.0f;
            l5 += (c == 5) ? 1.0f : 0.0f;
        }
    }
#pragma unroll
    for (int r = 0; r < 16; ++r) chosen[r * 64 + lane] = ch[r];
}

// logits_final = w * logits_e[chosen]; D one-hot. softmax over a single finite
// entry == 1; w = 1/(1+1e-12) == 1.0f in fp32.
__global__ void final_k(const float* __restrict__ logitsE, const int* __restrict__ chosen,
                        float* __restrict__ out) {
    int b = blockIdx.x * 256 + threadIdx.x;
    if (b >= B_) return;
    int c = chosen[b];
    const float w = 1.0f / (1.0f + 1e-12f);
    const float* lp = logitsE + ((long)c * B_ + b) * 10;
#pragma unroll
    for (int k = 0; k < 10; ++k) out[b * 10 + k] = lp[k] * w;
    float* Dp = out + B_ * 10 + B_ * E_ + b * E_;
#pragma unroll
    for (int e = 0; e < E_; ++e) Dp[e] = (e == c) ? 1.0f : 0.0f;
}

// ---------------------------------------------------------------------------
extern "C" void kernel_launch(void* const* d_in, const int* in_sizes, int n_in,
                              void* d_out, int out_size, void* d_ws, size_t ws_size,
                              hipStream_t stream) {
    (void)in_sizes; (void)n_in; (void)out_size; (void)ws_size;
    const float* x     = (const float*)d_in[0];
    const float* t_c1w = (const float*)d_in[1];
    const float* t_b1g = (const float*)d_in[2];
    const float* t_b1b = (const float*)d_in[3];
    const float* t_c2w = (const float*)d_in[4];
    const float* t_b2g = (const float*)d_in[5];
    const float* t_b2b = (const float*)d_in[6];
    const float* t_fcw = (const float*)d_in[7];
    const float* t_fcb = (const float*)d_in[8];
    const float* g1w   = (const float*)d_in[9];
    const float* g1b   = (const float*)d_in[10];
    const float* g2w   = (const float*)d_in[11];
    const float* g2b   = (const float*)d_in[12];
    const float* e_c1w = (const float*)d_in[13];
    const float* e_c1b = (const float*)d_in[14];
    const float* e_b1g = (const float*)d_in[15];
    const float* e_b1b = (const float*)d_in[16];
    const float* e_c2w = (const float*)d_in[17];
    const float* e_c2b = (const float*)d_in[18];
    const float* e_b2g = (const float*)d_in[19];
    const float* e_b2b = (const float*)d_in[20];
    const float* e_c3w = (const float*)d_in[21];
    const float* e_c3b = (const float*)d_in[22];
    const float* e_b3g = (const float*)d_in[23];
    const float* e_b3b = (const float*)d_in[24];
    const float* e_c4w = (const float*)d_in[25];
    const float* e_c4b = (const float*)d_in[26];
    const float* e_b4g = (const float*)d_in[27];
    const float* e_b4b = (const float*)d_in[28];
    const float* e_c5w = (const float*)d_in[29];
    const float* e_c5b = (const float*)d_in[30];
    const float* e_b5g = (const float*)d_in[31];
    const float* e_b5b = (const float*)d_in[32];
    const float* e_fw  = (const float*)d_in[33];
    const float* e_fb  = (const float*)d_in[34];
    const float* e_cw  = (const float*)d_in[35];
    const float* e_cb  = (const float*)d_in[36];
    const float* ema   = (const float*)d_in[37];
    float* out = (float*)d_out;
    float* ws  = (float*)d_ws;

    // workspace layout (floats)
    size_t o = 0;
    float* bufA    = ws + o; o += 16777216;   // 64 MB ping (half-batch t1 / c2 / c4 out)
    float* bufB    = ws + o; o += 8388608;    // 32 MB pong (t2-pool / c1 / c3 / c5 out)
    float* rf_in   = ws + o; o += B_ * 128;
    float* rf      = ws + o; o += B_ * 64;
    float* gv      = ws + o; o += B_ * 32;
    float* gate    = ws + o; o += B_ * E_;
    float* logitsE = ws + o; o += E_ * B_ * 10;
    float* feat    = ws + o; o += B_ * 128;
    float* fv      = ws + o; o += B_ * 128;
    int*   chosen  = (int*)(ws + o); o += B_;
    float* wt_t1 = ws + o; o += 864;
    float* bt_t1 = ws + o; o += 32;
    float* wt_t2 = ws + o; o += 9216;
    float* bt_t2 = ws + o; o += 32;
    float* wt_c1 = ws + o; o += 6 * 864;
    float* bt_c1 = ws + o; o += 6 * 32;
    float* wt_c2 = ws + o; o += 6 * 18432;
    float* bt_c2 = ws + o; o += 6 * 64;
    float* wt_c3 = ws + o; o += 6 * 36864;
    float* bt_c3 = ws + o; o += 6 * 64;
    float* wt_c4 = ws + o; o += 6 * 73728;
    float* bt_c4 = ws + o; o += 6 * 128;
    float* wt_c5 = ws + o; o += 6 * 147456;
    float* bt_c5 = ws + o; o += 6 * 128;

    // ---- weight prep (fold BN, transpose to [ci][k][co]) ----
    auto gsz = [](int n) { return (n + 255) / 256; };
    prep_w<<<gsz(864), 256, 0, stream>>>(t_c1w, t_b1g, wt_t1, 32, 3, 864);
    prep_b<<<1, 256, 0, stream>>>(nullptr, t_b1g, t_b1b, bt_t1, 32);
    prep_w<<<gsz(9216), 256, 0, stream>>>(t_c2w, t_b2g, wt_t2, 32, 32, 9216);
    prep_b<<<1, 256, 0, stream>>>(nullptr, t_b2g, t_b2b, bt_t2, 32);
    prep_w<<<gsz(5184), 256, 0, stream>>>(e_c1w, e_b1g, wt_c1, 32, 3, 5184);
    prep_b<<<1, 256, 0, stream>>>(e_c1b, e_b1g, e_b1b, bt_c1, 192);
    prep_w<<<gsz(110592), 256, 0, stream>>>(e_c2w, e_b2g, wt_c2, 64, 32, 110592);
    prep_b<<<2, 256, 0, stream>>>(e_c2b, e_b2g, e_b2b, bt_c2, 384);
    prep_w<<<gsz(221184), 256, 0, stream>>>(e_c3w, e_b3g, wt_c3, 64, 64, 221184);
    prep_b<<<2, 256, 0, stream>>>(e_c3b, e_b3g, e_b3b, bt_c3, 384);
    prep_w<<<gsz(442368), 256, 0, stream>>>(e_c4w, e_b4g, wt_c4, 128, 64, 442368);
    prep_b<<<3, 256, 0, stream>>>(e_c4b, e_b4g, e_b4b, bt_c4, 768);
    prep_w<<<gsz(884736), 256, 0, stream>>>(e_c5w, e_b5g, wt_c5, 128, 128, 884736);
    prep_b<<<3, 256, 0, stream>>>(e_c5b, e_b5g, e_b5b, bt_c5, 768);

    // ---- routing trunk (2 batch-halves to cap bufA at 64 MB) ----
    for (int q = 0; q < 2; ++q) {
        const float* xq = x + (size_t)q * 512 * 3 * 1024;
        conv3x3<3, 32, 32, 16, 32, 3, false><<<512 * 4, 256, 0, stream>>>(xq, wt_t1, bt_t1, bufA);
        conv3x3<32, 32, 32, 16, 8, 32, true><<<512 * 4, 256, 0, stream>>>(
            bufA, wt_t2, bt_t2, bufB + (size_t)q * 512 * 32 * 256);
    }
    trunk_pool<<<512, 256, 0, stream>>>(bufB, rf_in);
    fc_k<128, 64, true><<<256, 256, 0, stream>>>(rf_in, t_fcw, t_fcb, rf);
    fc_k<64, 32, true><<<128, 256, 0, stream>>>(rf, g1w, g1b, gv);
    fc_k<32, 6, false><<<24, 256, 0, stream>>>(gv, g2w, g2b, gate);

    // ---- experts (dense over full batch), one at a time ----
    for (int e = 0; e < E_; ++e) {
        conv3x3<3, 32, 32, 16, 8, 3, true><<<B_ * 4, 256, 0, stream>>>(
            x, wt_c1 + e * 864, bt_c1 + e * 32, bufB);
        conv3x3<32, 64, 16, 16, 32, 32, false><<<B_, 256, 0, stream>>>(
            bufB, wt_c2 + e * 18432, bt_c2 + e * 64, bufA);
        conv3x3<64, 64, 16, 16, 16, 32, true><<<B_, 256, 0, stream>>>(
            bufA, wt_c3 + e * 36864, bt_c3 + e * 64, bufB);
        conv3x3<64, 128, 8, 8, 32, 64, false><<<B_, 256, 0, stream>>>(
            bufB, wt_c4 + e * 73728, bt_c4 + e * 128, bufA);
        conv3x3<128, 128, 8, 8, 32, 128, false><<<B_, 256, 0, stream>>>(
            bufA, wt_c5 + e * 147456, bt_c5 + e * 128, bufB);
        gap_k<<<512, 256, 0, stream>>>(bufB, feat, 128, 64);
        fc_k<128, 128, true><<<512, 256, 0, stream>>>(feat, e_fw + e * 16384, e_fb + e * 128, fv);
        fc_k<128, 10, false><<<40, 256, 0, stream>>>(fv, e_cw + e * 1280, e_cb + e * 10,
                                                     logitsE + (size_t)e * B_ * 10);
    }

    // ---- scoring, dispatch, combine ----
    float* balanced = out + B_ * 10;  // second output region, also consumed below
    conf_bal_k<<<24, 256, 0, stream>>>(logitsE, gate, ema, balanced);
    dispatch_k<<<1, 64, 0, stream>>>(balanced, chosen);
    final_k<<<4, 256, 0, stream>>>(logitsE, chosen, out);
}

// Round 2
// 4868.765 us; speedup vs baseline: 1.3959x; 1.3959x over previous
//
#include <hip/hip_runtime.h>
#include <math.h>

#define B_ 1024
#define E_ 6
#define CAPF 192.0f

// ---------------------------------------------------------------------------
// Weight prep: fold BN (scale s = g/sqrt(1+eps)) into conv weights and bias,
// transpose weights [E][CO][CI][3][3] -> [E][CI][3][3][CO] (co contiguous so
// the conv inner loop does wave-uniform scalar loads).
// ---------------------------------------------------------------------------
__global__ void prep_w(const float* __restrict__ w, const float* __restrict__ g,
                       float* __restrict__ wout, int CO, int CI, int total) {
    int i = blockIdx.x * 256 + threadIdx.x;
    if (i >= total) return;
    int k = i % 9;
    int t = i / 9;
    int ci = t % CI; t /= CI;
    int co = t % CO;
    int e  = t / CO;
    float s = g[e * CO + co] * (1.0f / sqrtf(1.0f + 1e-5f));
    wout[(((long)(e * CI + ci) * 9 + k) * CO) + co] = w[i] * s;
}

__global__ void prep_b(const float* __restrict__ cb, const float* __restrict__ g,
                       const float* __restrict__ bb, float* __restrict__ bout, int N) {
    int i = blockIdx.x * 256 + threadIdx.x;
    if (i >= N) return;
    float s = g[i] * (1.0f / sqrtf(1.0f + 1e-5f));
    float c = (cb != nullptr) ? cb[i] : 0.0f;
    bout[i] = c * s + bb[i];
}

// ---------------------------------------------------------------------------
// Direct 3x3 conv (pad=1) + folded-BN bias + ReLU (+ optional fused 2x2 maxpool).
// Block = 256 threads handles one TSxTS conv tile of one image.
// CI_CHUNK kept small enough that LDS/block <= ~26KB -> 6-7 blocks/CU
// (grid gives 4 blocks/CU = 16 waves/CU) so s_load weight-latency stalls
// overlap across waves.
// ---------------------------------------------------------------------------
template <int CI, int CO, int H, int TS, int CO_BLK, int CI_CHUNK, bool POOL>
__launch_bounds__(256)
__global__ void conv3x3(const float* __restrict__ in, const float* __restrict__ wt,
                        const float* __restrict__ bias, float* __restrict__ out) {
    constexpr int TD = H / TS;
    constexpr int TILES = TD * TD;
    constexpr int LW = TS + 2;
    constexpr int NPX = POOL ? (TS / 2) * (TS / 2) : TS * TS;
    constexpr int G = 256 / NPX;          // co groups handled in parallel by threads
    constexpr int NG = CO / CO_BLK;       // total co groups
    constexpr int GPT = NG / G;           // groups per thread (serial)
    constexpr int COT = GPT * CO_BLK;     // co per thread
    constexpr int NW = POOL ? 4 : 1;      // conv px per thread
    constexpr int OD = POOL ? TS / 2 : TS;

    __shared__ float lds[CI_CHUNK * LW * LW];

    int bid = blockIdx.x;
    int n = bid / TILES;
    int t = bid % TILES;
    int ty = (t / TD) * TS;
    int tx = (t % TD) * TS;
    int tid = threadIdx.x;
    int px = tid % NPX;
    int cg0 = tid / NPX;                      // wave-uniform by construction
    const int cg0s = __builtin_amdgcn_readfirstlane(cg0);
    int oy = px / OD;
    int ox = px % OD;

    float acc[NW][COT];
#pragma unroll
    for (int g2 = 0; g2 < GPT; ++g2)
#pragma unroll
        for (int j = 0; j < CO_BLK; ++j) {
            float bv = bias[(cg0s + g2 * G) * CO_BLK + j];
#pragma unroll
            for (int p = 0; p < NW; ++p) acc[p][g2 * CO_BLK + j] = bv;
        }

    for (int cc = 0; cc < CI / CI_CHUNK; ++cc) {
        const float* inb = in + ((long)n * CI + cc * CI_CHUNK) * (H * H);
        for (int idx = tid; idx < CI_CHUNK * LW * LW; idx += 256) {
            int ci = idx / (LW * LW);
            int r = idx - ci * (LW * LW);
            int yy = r / LW + ty - 1;
            int xx = r % LW + tx - 1;
            float v = 0.0f;
            if ((unsigned)yy < (unsigned)H && (unsigned)xx < (unsigned)H)
                v = inb[ci * H * H + yy * H + xx];
            lds[idx] = v;
        }
        __syncthreads();

        const float* wbase = wt + ((long)cc * CI_CHUNK) * 9 * CO;
        for (int ci = 0; ci < CI_CHUNK; ++ci) {
#pragma unroll
            for (int ky = 0; ky < 3; ++ky) {
#pragma unroll
                for (int kx = 0; kx < 3; ++kx) {
                    float v[NW];
                    if constexpr (POOL) {
#pragma unroll
                        for (int dy = 0; dy < 2; ++dy)
#pragma unroll
                            for (int dx = 0; dx < 2; ++dx)
                                v[dy * 2 + dx] =
                                    lds[ci * LW * LW + (2 * oy + dy + ky) * LW + (2 * ox + dx + kx)];
                    } else {
                        v[0] = lds[ci * LW * LW + (oy + ky) * LW + (ox + kx)];
                    }
                    const float* wr = wbase + ((ci * 3 + ky) * 3 + kx) * CO + cg0s * CO_BLK;
#pragma unroll
                    for (int g2 = 0; g2 < GPT; ++g2)
#pragma unroll
                        for (int j = 0; j < CO_BLK; ++j) {
                            float wv = wr[g2 * G * CO_BLK + j];
#pragma unroll
                            for (int p = 0; p < NW; ++p)
                                acc[p][g2 * CO_BLK + j] = fmaf(v[p], wv, acc[p][g2 * CO_BLK + j]);
                        }
                }
            }
        }
        __syncthreads();
    }

    if constexpr (POOL) {
        constexpr int HP = H / 2;
        int py = ty / 2 + oy;
        int pxx = tx / 2 + ox;
#pragma unroll
        for (int g2 = 0; g2 < GPT; ++g2)
#pragma unroll
            for (int j = 0; j < CO_BLK; ++j) {
                int co = (cg0s + g2 * G) * CO_BLK + j;
                int a = g2 * CO_BLK + j;
                float m = fmaxf(fmaxf(acc[0][a], acc[1][a]), fmaxf(acc[2][a], acc[3][a]));
                out[((long)n * CO + co) * (HP * HP) + py * HP + pxx] = fmaxf(m, 0.0f);
            }
    } else {
        int yy = ty + oy;
        int xx = tx + ox;
#pragma unroll
        for (int g2 = 0; g2 < GPT; ++g2)
#pragma unroll
            for (int j = 0; j < CO_BLK; ++j) {
                int co = (cg0s + g2 * G) * CO_BLK + j;
                out[((long)n * CO + co) * (H * H) + yy * H + xx] =
                    fmaxf(acc[0][g2 * CO_BLK + j], 0.0f);
            }
    }
}

// ---------------------------------------------------------------------------
// Trunk pooling: [B,32,16,16] -> avgpool 16x16 -> 2x2
// ---------------------------------------------------------------------------
__global__ void trunk_pool(const float* __restrict__ in, float* __restrict__ out) {
    int g = blockIdx.x * 256 + threadIdx.x;
    if (g >= B_ * 128) return;
    int n = g >> 7;
    int r = g & 127;
    int c = r >> 2;
    int i = (r >> 1) & 1;
    int j = r & 1;
    const float* p = in + ((long)n * 32 + c) * 256 + i * 8 * 16 + j * 8;
    float s = 0.0f;
#pragma unroll
    for (int y = 0; y < 8; ++y)
#pragma unroll
        for (int x = 0; x < 8; ++x) s += p[y * 16 + x];
    out[g] = s * (1.0f / 64.0f);
}

// Global average pool over 64 elems: wave-per-row, coalesced, shuffle reduce.
// in [ROWS, 64] -> out [ROWS]
__global__ void gap_k(const float* __restrict__ in, float* __restrict__ out, int rows) {
    int w = (blockIdx.x * 256 + threadIdx.x) >> 6;
    int lane = threadIdx.x & 63;
    if (w >= rows) return;
    float v = in[(long)w * 64 + lane];
#pragma unroll
    for (int off = 32; off > 0; off >>= 1) v += __shfl_down(v, off);
    if (lane == 0) out[w] = v * (1.0f / 64.0f);
}

// FC: out[n,o] = (relu)( in[n,:] . W[o,:] + b[o] ),  W row-major [O][I]
template <int I, int O, bool RELU>
__global__ void fc_k(const float* __restrict__ in, const float* __restrict__ W,
                     const float* __restrict__ bias, float* __restrict__ out) {
    int g = blockIdx.x * 256 + threadIdx.x;
    if (g >= B_ * O) return;
    int n = g / O;
    int o = g - n * O;
    const float* ip = in + (long)n * I;
    const float* wp = W + (long)o * I;
    float a = bias[o];
#pragma unroll 8
    for (int k = 0; k < I; ++k) a = fmaf(ip[k], wp[k], a);
    if (RELU) a = fmaxf(a, 0.0f);
    out[g] = a;
}

// conf = sum p*log(p+1e-12) from log_softmax of logits; then balanced score.
__global__ void conf_bal_k(const float* __restrict__ logitsE, const float* __restrict__ gate,
                           const float* __restrict__ ema, float* __restrict__ balanced) {
    int g = blockIdx.x * 256 + threadIdx.x;
    if (g >= B_ * E_) return;
    int b = g / E_;
    int e = g - b * E_;
    const float* lp = logitsE + ((long)e * B_ + b) * 10;
    float m = lp[0];
#pragma unroll
    for (int k = 1; k < 10; ++k) m = fmaxf(m, lp[k]);
    float s = 0.0f;
#pragma unroll
    for (int k = 0; k < 10; ++k) s += expf(lp[k] - m);
    float ls = m + logf(s);
    float conf = 0.0f;
#pragma unroll
    for (int k = 0; k < 10; ++k) {
        float p = expf(lp[k] - ls);
        conf += p * logf(p + 1e-12f);
    }
    float em = ema[e];
    float boost = (em < 0.05f) ? (0.05f - em) * 10.0f : 0.0f;
    float comb = 0.7f * gate[b * E_ + e] + 0.3f * conf + boost;
    balanced[g] = comb - 2.0f * em;
}

__device__ __forceinline__ float load_sel(int i, float l0, float l1, float l2, float l3,
                                          float l4, float l5) {
    float r = l0;
    r = (i == 1) ? l1 : r;
    r = (i == 2) ? l2 : r;
    r = (i == 3) ? l3 : r;
    r = (i == 4) ? l4 : r;
    r = (i == 5) ? l5 : r;
    return r;
}

// Sequential greedy capacity-constrained dispatch. Single wave (64 lanes).
__global__ void dispatch_k(const float* __restrict__ balanced, int* __restrict__ chosen) {
    int lane = threadIdx.x;
    int t0[16], t1[16], ch[16];
#pragma unroll
    for (int r = 0; r < 16; ++r) {
        int b = r * 64 + lane;
        const float* bp = balanced + b * E_;
        float v[E_];
#pragma unroll
        for (int e = 0; e < E_; ++e) v[e] = bp[e];
        int i0 = 0;
        float m0 = v[0];
#pragma unroll
        for (int e = 1; e < E_; ++e)
            if (v[e] > m0) { m0 = v[e]; i0 = e; }
        int i1 = -1;
        float m1 = -1e38f;
#pragma unroll
        for (int e = 0; e < E_; ++e)
            if (e != i0 && v[e] > m1) { m1 = v[e]; i1 = e; }
        t0[r] = i0;
        t1[r] = i1;
    }
    float l0 = 0, l1 = 0, l2 = 0, l3 = 0, l4 = 0, l5 = 0;
#pragma unroll
    for (int r = 0; r < 16; ++r) {
        for (int q = 0; q < 64; ++q) {
            int i0 = __shfl(t0[r], q);
            int i1 = __shfl(t1[r], q);
            float a0 = load_sel(i0, l0, l1, l2, l3, l4, l5);
            float a1 = load_sel(i1, l0, l1, l2, l3, l4, l5);
            bool f0 = a0 < CAPF;
            bool f1 = a1 < CAPF;
            int fb = (a1 < a0) ? i1 : i0;      // argmin, first on tie
            int c = f0 ? i0 : (f1 ? i1 : fb);  // argmax(fits), first True
            if (lane == q) ch[r] = c;
            l0 += (c == 0) ? 1.0f : 0.0f;
            l1 += (c == 1) ? 1.0f : 0.0f;
            l2 += (c == 2) ? 1.0f : 0.0f;
            l3 += (c == 3) ? 1.0f : 0.0f;
            l4 += (c == 4) ? 1.0f : 0.0f;
            l5 += (c == 5) ? 1.0f : 0.0f;
        }
    }
#pragma unroll
    for (int r = 0; r < 16; ++r) chosen[r * 64 + lane] = ch[r];
}

__global__ void final_k(const float* __restrict__ logitsE, const int* __restrict__ chosen,
                        float* __restrict__ out) {
    int b = blockIdx.x * 256 + threadIdx.x;
    if (b >= B_) return;
    int c = chosen[b];
    const float w = 1.0f / (1.0f + 1e-12f);
    const float* lp = logitsE + ((long)c * B_ + b) * 10;
#pragma unroll
    for (int k = 0; k < 10; ++k) out[b * 10 + k] = lp[k] * w;
    float* Dp = out + B_ * 10 + B_ * E_ + b * E_;
#pragma unroll
    for (int e = 0; e < E_; ++e) Dp[e] = (e == c) ? 1.0f : 0.0f;
}

// ---------------------------------------------------------------------------
extern "C" void kernel_launch(void* const* d_in, const int* in_sizes, int n_in,
                              void* d_out, int out_size, void* d_ws, size_t ws_size,
                              hipStream_t stream) {
    (void)in_sizes; (void)n_in; (void)out_size; (void)ws_size;
    const float* x     = (const float*)d_in[0];
    const float* t_c1w = (const float*)d_in[1];
    const float* t_b1g = (const float*)d_in[2];
    const float* t_b1b = (const float*)d_in[3];
    const float* t_c2w = (const float*)d_in[4];
    const float* t_b2g = (const float*)d_in[5];
    const float* t_b2b = (const float*)d_in[6];
    const float* t_fcw = (const float*)d_in[7];
    const float* t_fcb = (const float*)d_in[8];
    const float* g1w   = (const float*)d_in[9];
    const float* g1b   = (const float*)d_in[10];
    const float* g2w   = (const float*)d_in[11];
    const float* g2b   = (const float*)d_in[12];
    const float* e_c1w = (const float*)d_in[13];
    const float* e_c1b = (const float*)d_in[14];
    const float* e_b1g = (const float*)d_in[15];
    const float* e_b1b = (const float*)d_in[16];
    const float* e_c2w = (const float*)d_in[17];
    const float* e_c2b = (const float*)d_in[18];
    const float* e_b2g = (const float*)d_in[19];
    const float* e_b2b = (const float*)d_in[20];
    const float* e_c3w = (const float*)d_in[21];
    const float* e_c3b = (const float*)d_in[22];
    const float* e_b3g = (const float*)d_in[23];
    const float* e_b3b = (const float*)d_in[24];
    const float* e_c4w = (const float*)d_in[25];
    const float* e_c4b = (const float*)d_in[26];
    const float* e_b4g = (const float*)d_in[27];
    const float* e_b4b = (const float*)d_in[28];
    const float* e_c5w = (const float*)d_in[29];
    const float* e_c5b = (const float*)d_in[30];
    const float* e_b5g = (const float*)d_in[31];
    const float* e_b5b = (const float*)d_in[32];
    const float* e_fw  = (const float*)d_in[33];
    const float* e_fb  = (const float*)d_in[34];
    const float* e_cw  = (const float*)d_in[35];
    const float* e_cb  = (const float*)d_in[36];
    const float* ema   = (const float*)d_in[37];
    float* out = (float*)d_out;
    float* ws  = (float*)d_ws;

    // workspace layout (floats)
    size_t o = 0;
    float* bufA    = ws + o; o += 16777216;   // 64 MB ping
    float* bufB    = ws + o; o += 8388608;    // 32 MB pong
    float* rf_in   = ws + o; o += B_ * 128;
    float* rf      = ws + o; o += B_ * 64;
    float* gv      = ws + o; o += B_ * 32;
    float* gate    = ws + o; o += B_ * E_;
    float* logitsE = ws + o; o += E_ * B_ * 10;
    float* feat    = ws + o; o += B_ * 128;
    float* fv      = ws + o; o += B_ * 128;
    int*   chosen  = (int*)(ws + o); o += B_;
    float* wt_t1 = ws + o; o += 864;
    float* bt_t1 = ws + o; o += 32;
    float* wt_t2 = ws + o; o += 9216;
    float* bt_t2 = ws + o; o += 32;
    float* wt_c1 = ws + o; o += 6 * 864;
    float* bt_c1 = ws + o; o += 6 * 32;
    float* wt_c2 = ws + o; o += 6 * 18432;
    float* bt_c2 = ws + o; o += 6 * 64;
    float* wt_c3 = ws + o; o += 6 * 36864;
    float* bt_c3 = ws + o; o += 6 * 64;
    float* wt_c4 = ws + o; o += 6 * 73728;
    float* bt_c4 = ws + o; o += 6 * 128;
    float* wt_c5 = ws + o; o += 6 * 147456;
    float* bt_c5 = ws + o; o += 6 * 128;

    // ---- weight prep ----
    auto gsz = [](int n) { return (n + 255) / 256; };
    prep_w<<<gsz(864), 256, 0, stream>>>(t_c1w, t_b1g, wt_t1, 32, 3, 864);
    prep_b<<<1, 256, 0, stream>>>(nullptr, t_b1g, t_b1b, bt_t1, 32);
    prep_w<<<gsz(9216), 256, 0, stream>>>(t_c2w, t_b2g, wt_t2, 32, 32, 9216);
    prep_b<<<1, 256, 0, stream>>>(nullptr, t_b2g, t_b2b, bt_t2, 32);
    prep_w<<<gsz(5184), 256, 0, stream>>>(e_c1w, e_b1g, wt_c1, 32, 3, 5184);
    prep_b<<<1, 256, 0, stream>>>(e_c1b, e_b1g, e_b1b, bt_c1, 192);
    prep_w<<<gsz(110592), 256, 0, stream>>>(e_c2w, e_b2g, wt_c2, 64, 32, 110592);
    prep_b<<<2, 256, 0, stream>>>(e_c2b, e_b2g, e_b2b, bt_c2, 384);
    prep_w<<<gsz(221184), 256, 0, stream>>>(e_c3w, e_b3g, wt_c3, 64, 64, 221184);
    prep_b<<<2, 256, 0, stream>>>(e_c3b, e_b3g, e_b3b, bt_c3, 384);
    prep_w<<<gsz(442368), 256, 0, stream>>>(e_c4w, e_b4g, wt_c4, 128, 64, 442368);
    prep_b<<<3, 256, 0, stream>>>(e_c4b, e_b4g, e_b4b, bt_c4, 768);
    prep_w<<<gsz(884736), 256, 0, stream>>>(e_c5w, e_b5g, wt_c5, 128, 128, 884736);
    prep_b<<<3, 256, 0, stream>>>(e_c5b, e_b5g, e_b5b, bt_c5, 768);

    // ---- routing trunk (2 batch-halves) ----
    for (int q = 0; q < 2; ++q) {
        const float* xq = x + (size_t)q * 512 * 3 * 1024;
        conv3x3<3, 32, 32, 16, 32, 3, false><<<512 * 4, 256, 0, stream>>>(xq, wt_t1, bt_t1, bufA);
        conv3x3<32, 32, 32, 16, 8, 16, true><<<512 * 4, 256, 0, stream>>>(
            bufA, wt_t2, bt_t2, bufB + (size_t)q * 512 * 32 * 256);
    }
    trunk_pool<<<512, 256, 0, stream>>>(bufB, rf_in);
    fc_k<128, 64, true><<<256, 256, 0, stream>>>(rf_in, t_fcw, t_fcb, rf);
    fc_k<64, 32, true><<<128, 256, 0, stream>>>(rf, g1w, g1b, gv);
    fc_k<32, 6, false><<<24, 256, 0, stream>>>(gv, g2w, g2b, gate);

    // ---- experts (dense over full batch) ----
    for (int e = 0; e < E_; ++e) {
        conv3x3<3, 32, 32, 16, 8, 3, true><<<B_ * 4, 256, 0, stream>>>(
            x, wt_c1 + e * 864, bt_c1 + e * 32, bufB);
        conv3x3<32, 64, 16, 16, 32, 16, false><<<B_, 256, 0, stream>>>(
            bufB, wt_c2 + e * 18432, bt_c2 + e * 64, bufA);
        conv3x3<64, 64, 16, 16, 16, 16, true><<<B_, 256, 0, stream>>>(
            bufA, wt_c3 + e * 36864, bt_c3 + e * 64, bufB);
        conv3x3<64, 128, 8, 8, 32, 64, false><<<B_, 256, 0, stream>>>(
            bufB, wt_c4 + e * 73728, bt_c4 + e * 128, bufA);
        conv3x3<128, 128, 8, 8, 32, 64, false><<<B_, 256, 0, stream>>>(
            bufA, wt_c5 + e * 147456, bt_c5 + e * 128, bufB);
        gap_k<<<B_ * 128 / 4, 256, 0, stream>>>(bufB, feat, B_ * 128);
        fc_k<128, 128, true><<<512, 256, 0, stream>>>(feat, e_fw + e * 16384, e_fb + e * 128, fv);
        fc_k<128, 10, false><<<40, 256, 0, stream>>>(fv, e_cw + e * 1280, e_cb + e * 10,
                                                     logitsE + (size_t)e * B_ * 10);
    }

    // ---- scoring, dispatch, combine ----
    float* balanced = out + B_ * 10;
    conf_bal_k<<<24, 256, 0, stream>>>(logitsE, gate, ema, balanced);
    dispatch_k<<<1, 64, 0, stream>>>(balanced, chosen);
    final_k<<<4, 256, 0, stream>>>(logitsE, chosen, out);
}

// Round 4
// 3554.880 us; speedup vs baseline: 1.9119x; 1.3696x over previous
//
#include <hip/hip_runtime.h>
#include <math.h>

#define B_ 1024
#define E_ 6
#define CAPF 192.0f

typedef _Float16 half8 __attribute__((ext_vector_type(8)));
typedef float f32x4 __attribute__((ext_vector_type(4)));

__device__ __forceinline__ unsigned short h_bits(_Float16 h) {
    union { _Float16 f; unsigned short u; } c; c.f = h; return c.u;
}
// pack fp32 -> (hi fp16 | lo fp16<<16), lo prescaled by 2048 to avoid fp16 subnormals
__device__ __forceinline__ unsigned int splitpack(float v) {
    _Float16 h = (_Float16)v;
    _Float16 l = (_Float16)((v - (float)h) * 2048.0f);
    return (unsigned int)h_bits(h) | ((unsigned int)h_bits(l) << 16);
}

// ---------------------------------------------------------------------------
// Old-style weight prep (trunk + c1..c3): fold BN, transpose to [ci][k][co].
// ---------------------------------------------------------------------------
__global__ void prep_w(const float* __restrict__ w, const float* __restrict__ g,
                       float* __restrict__ wout, int CO, int CI, int total) {
    int i = blockIdx.x * 256 + threadIdx.x;
    if (i >= total) return;
    int k = i % 9;
    int t = i / 9;
    int ci = t % CI; t /= CI;
    int co = t % CO;
    int e  = t / CO;
    float s = g[e * CO + co] * (1.0f / sqrtf(1.0f + 1e-5f));
    wout[(((long)(e * CI + ci) * 9 + k) * CO) + co] = w[i] * s;
}

__global__ void prep_b(const float* __restrict__ cb, const float* __restrict__ g,
                       const float* __restrict__ bb, float* __restrict__ bout, int N) {
    int i = blockIdx.x * 256 + threadIdx.x;
    if (i >= N) return;
    float s = g[i] * (1.0f / sqrtf(1.0f + 1e-5f));
    float c = (cb != nullptr) ? cb[i] : 0.0f;
    bout[i] = c * s + bb[i];
}

// ---------------------------------------------------------------------------
// MFMA weight prep (c4/c5): fold BN, split fp16 hi/lo (lo*2048), store in exact
// B-fragment order: [e][nbg 8][tap 9][chunk NC][plane 2][lane 64][j 8].
// B[k][n]: n = lane&15 (co within 16-block), k = (lane>>4)*8+j (ci within chunk).
// total = 6*8*9*NC*512 threads; each thread writes BOTH hi and lo planes.
// ---------------------------------------------------------------------------
__global__ void prep_wfrag(const float* __restrict__ w, const float* __restrict__ g,
                           _Float16* __restrict__ out, int CI, int total) {
    int i = blockIdx.x * 256 + threadIdx.x;
    if (i >= total) return;
    const int NC = CI / 32;
    int j = i & 7;
    int lane = (i >> 3) & 63;
    int rest = i >> 9;
    int chunk = rest % NC; rest /= NC;
    int tap = rest % 9; rest /= 9;
    int nbg = rest & 7;
    int e = rest >> 3;
    int co = nbg * 16 + (lane & 15);
    int ci = chunk * 32 + ((lane >> 4) * 8) + j;
    float s = g[e * 128 + co] * (1.0f / sqrtf(1.0f + 1e-5f));
    float v = w[(((long)(e * 128 + co) * CI + ci) * 9) + tap] * s;
    _Float16 hi = (_Float16)v;
    _Float16 lo = (_Float16)((v - (float)hi) * 2048.0f);
    long perE = (long)8 * 9 * NC * 2 * 512;
    long F0 = ((long)(nbg * 9 + tap) * NC + chunk) * 2;
    long base = e * perE + F0 * 512 + lane * 8 + j;
    out[base] = hi;
    out[base + 512] = lo;
}

// ---------------------------------------------------------------------------
// Old direct conv (kept for trunk + c1..c3).
// ---------------------------------------------------------------------------
template <int CI, int CO, int H, int TS, int CO_BLK, int CI_CHUNK, bool POOL>
__launch_bounds__(256)
__global__ void conv3x3(const float* __restrict__ in, const float* __restrict__ wt,
                        const float* __restrict__ bias, float* __restrict__ out) {
    constexpr int TD = H / TS;
    constexpr int TILES = TD * TD;
    constexpr int LW = TS + 2;
    constexpr int NPX = POOL ? (TS / 2) * (TS / 2) : TS * TS;
    constexpr int G = 256 / NPX;
    constexpr int NG = CO / CO_BLK;
    constexpr int GPT = NG / G;
    constexpr int COT = GPT * CO_BLK;
    constexpr int NW = POOL ? 4 : 1;
    constexpr int OD = POOL ? TS / 2 : TS;

    __shared__ float lds[CI_CHUNK * LW * LW];

    int bid = blockIdx.x;
    int n = bid / TILES;
    int t = bid % TILES;
    int ty = (t / TD) * TS;
    int tx = (t % TD) * TS;
    int tid = threadIdx.x;
    int px = tid % NPX;
    int cg0 = tid / NPX;
    const int cg0s = __builtin_amdgcn_readfirstlane(cg0);
    int oy = px / OD;
    int ox = px % OD;

    float acc[NW][COT];
#pragma unroll
    for (int g2 = 0; g2 < GPT; ++g2)
#pragma unroll
        for (int j = 0; j < CO_BLK; ++j) {
            float bv = bias[(cg0s + g2 * G) * CO_BLK + j];
#pragma unroll
            for (int p = 0; p < NW; ++p) acc[p][g2 * CO_BLK + j] = bv;
        }

    for (int cc = 0; cc < CI / CI_CHUNK; ++cc) {
        const float* inb = in + ((long)n * CI + cc * CI_CHUNK) * (H * H);
        for (int idx = tid; idx < CI_CHUNK * LW * LW; idx += 256) {
            int ci = idx / (LW * LW);
            int r = idx - ci * (LW * LW);
            int yy = r / LW + ty - 1;
            int xx = r % LW + tx - 1;
            float v = 0.0f;
            if ((unsigned)yy < (unsigned)H && (unsigned)xx < (unsigned)H)
                v = inb[ci * H * H + yy * H + xx];
            lds[idx] = v;
        }
        __syncthreads();

        const float* wbase = wt + ((long)cc * CI_CHUNK) * 9 * CO;
        for (int ci = 0; ci < CI_CHUNK; ++ci) {
#pragma unroll
            for (int ky = 0; ky < 3; ++ky) {
#pragma unroll
                for (int kx = 0; kx < 3; ++kx) {
                    float v[NW];
                    if constexpr (POOL) {
#pragma unroll
                        for (int dy = 0; dy < 2; ++dy)
#pragma unroll
                            for (int dx = 0; dx < 2; ++dx)
                                v[dy * 2 + dx] =
                                    lds[ci * LW * LW + (2 * oy + dy + ky) * LW + (2 * ox + dx + kx)];
                    } else {
                        v[0] = lds[ci * LW * LW + (oy + ky) * LW + (ox + kx)];
                    }
                    const float* wr = wbase + ((ci * 3 + ky) * 3 + kx) * CO + cg0s * CO_BLK;
#pragma unroll
                    for (int g2 = 0; g2 < GPT; ++g2)
#pragma unroll
                        for (int j = 0; j < CO_BLK; ++j) {
                            float wv = wr[g2 * G * CO_BLK + j];
#pragma unroll
                            for (int p = 0; p < NW; ++p)
                                acc[p][g2 * CO_BLK + j] = fmaf(v[p], wv, acc[p][g2 * CO_BLK + j]);
                        }
                }
            }
        }
        __syncthreads();
    }

    if constexpr (POOL) {
        constexpr int HP = H / 2;
        int py = ty / 2 + oy;
        int pxx = tx / 2 + ox;
#pragma unroll
        for (int g2 = 0; g2 < GPT; ++g2)
#pragma unroll
            for (int j = 0; j < CO_BLK; ++j) {
                int co = (cg0s + g2 * G) * CO_BLK + j;
                int a = g2 * CO_BLK + j;
                float m = fmaxf(fmaxf(acc[0][a], acc[1][a]), fmaxf(acc[2][a], acc[3][a]));
                out[((long)n * CO + co) * (HP * HP) + py * HP + pxx] = fmaxf(m, 0.0f);
            }
    } else {
        int yy = ty + oy;
        int xx = tx + ox;
#pragma unroll
        for (int g2 = 0; g2 < GPT; ++g2)
#pragma unroll
            for (int j = 0; j < CO_BLK; ++j) {
                int co = (cg0s + g2 * G) * CO_BLK + j;
                out[((long)n * CO + co) * (H * H) + yy * H + xx] =
                    fmaxf(acc[0][g2 * CO_BLK + j], 0.0f);
            }
    }
}

// ---------------------------------------------------------------------------
// Repack c3 output: NCHW fp32 [n][64][8][8] -> NHWC packed fp16-pair dwords
// [n][px 64][c 64]. LDS transpose so both global sides are coalesced.
// ---------------------------------------------------------------------------
__global__ void repack_k(const float* __restrict__ in, unsigned int* __restrict__ out) {
    __shared__ float t[64 * 65];
    int n = blockIdx.x;
    const float* ip = in + (long)n * 4096;
    for (int u = threadIdx.x; u < 4096; u += 256) {
        int px = u & 63, cc = u >> 6;
        t[px * 65 + cc] = ip[cc * 64 + px];
    }
    __syncthreads();
    for (int u = threadIdx.x; u < 4096; u += 256) {
        int c = u & 63, px = u >> 6;
        out[(long)n * 4096 + px * 64 + c] = splitpack(t[px * 65 + c]);
    }
}

// ---------------------------------------------------------------------------
// MFMA conv 3x3 (8x8 spatial), split-fp16, implicit GEMM D[px][co].
// Block: 256 thr = 4 waves; 2 images (128 px) x 128 co.
// Wave w: ph=w&1 -> px-half (4 m-blocks), ch=w>>1 -> co-half (4 n-blocks).
// In: packed pair dwords NHWC [n][64][CI]. Out: packed pairs (c4) or fp32 (c5),
// both NHWC [n][64][128].
// ---------------------------------------------------------------------------
template <int CI, int OUTF32>
__launch_bounds__(256, 2)
__global__ void conv_mfma(const unsigned int* __restrict__ in,
                          const _Float16* __restrict__ wt,
                          const float* __restrict__ bias, void* __restrict__ outv) {
    constexpr int NC = CI / 32;
    constexpr int PXS = 40;  // LDS pixel stride in f16 (16B-aligned, bank-uniform)
    __shared__ _Float16 ldsH[2 * 100 * PXS];
    __shared__ _Float16 ldsL[2 * 100 * PXS];

    const int tid = threadIdx.x;
    const int wv = tid >> 6, lane = tid & 63;
    const int ph = wv & 1, ch = wv >> 1;
    const int q = lane >> 4, l15 = lane & 15;
    const int n0 = blockIdx.x * 2;

    // zero LDS (halo stays zero across chunks)
    {
        half8 z = {};
        half8* zh = (half8*)ldsH;
        half8* zl = (half8*)ldsL;
        for (int i = tid; i < 2 * 100 * PXS / 8; i += 256) { zh[i] = z; zl[i] = z; }
    }

    f32x4 accH[16], accL[16];
#pragma unroll
    for (int i = 0; i < 16; ++i) { accH[i] = (f32x4){0,0,0,0}; accL[i] = (f32x4){0,0,0,0}; }

    for (int c = 0; c < NC; ++c) {
        __syncthreads();  // LDS reuse + (c==0) zero-fill visibility
        // stage: 2 img x 64 px x 8 ci-quads, split planes
        for (int u = tid; u < 1024; u += 256) {
            int cu = u & 7;
            int px = (u >> 3) & 63;
            int img = u >> 9;
            long gidx = ((long)(n0 + img) * 64 + px) * CI + c * 32 + cu * 4;
            uint4 w = *(const uint4*)(in + gidx);
            unsigned int h01 = (w.x & 0xffffu) | (w.y << 16);
            unsigned int h23 = (w.z & 0xffffu) | (w.w << 16);
            unsigned int l01 = (w.x >> 16) | (w.y & 0xffff0000u);
            unsigned int l23 = (w.z >> 16) | (w.w & 0xffff0000u);
            int py = px >> 3, pxx = px & 7;
            int fi = (img * 100 + (py + 1) * 10 + (pxx + 1)) * PXS + cu * 4;
            *(uint2*)(&ldsH[fi]) = make_uint2(h01, h23);
            *(uint2*)(&ldsL[fi]) = make_uint2(l01, l23);
        }
        __syncthreads();

#pragma unroll
        for (int ky = 0; ky < 3; ++ky)
#pragma unroll
            for (int kx = 0; kx < 3; ++kx) {
                const int tap = ky * 3 + kx;
                // A fragments (pixels): A[m][k], m=lane&15 (px), k=q*8+j (ci)
                half8 ah[4], al[4];
#pragma unroll
                for (int mb = 0; mb < 4; ++mb) {
                    int m = ph * 64 + mb * 16 + l15;
                    int img = m >> 6, py = (m >> 3) & 7, pxx = m & 7;
                    int fi = (img * 100 + (py + ky) * 10 + (pxx + kx)) * PXS + q * 8;
                    ah[mb] = *(const half8*)&ldsH[fi];
                    al[mb] = *(const half8*)&ldsL[fi];
                }
                // B fragments (weights) from fragment-ordered global array
                half8 bh[4], bl[4];
#pragma unroll
                for (int nb = 0; nb < 4; ++nb) {
                    int nbg = ch * 4 + nb;
                    int F0 = ((nbg * 9 + tap) * NC + c) * 2;
                    bh[nb] = ((const half8*)wt)[(long)F0 * 64 + lane];
                    bl[nb] = ((const half8*)wt)[(long)(F0 + 1) * 64 + lane];
                }
#pragma unroll
                for (int nb = 0; nb < 4; ++nb)
#pragma unroll
                    for (int mb = 0; mb < 4; ++mb)
                        accH[mb * 4 + nb] = __builtin_amdgcn_mfma_f32_16x16x32_f16(
                            ah[mb], bh[nb], accH[mb * 4 + nb], 0, 0, 0);
#pragma unroll
                for (int nb = 0; nb < 4; ++nb)
#pragma unroll
                    for (int mb = 0; mb < 4; ++mb)
                        accL[mb * 4 + nb] = __builtin_amdgcn_mfma_f32_16x16x32_f16(
                            ah[mb], bl[nb], accL[mb * 4 + nb], 0, 0, 0);
#pragma unroll
                for (int nb = 0; nb < 4; ++nb)
#pragma unroll
                    for (int mb = 0; mb < 4; ++mb)
                        accL[mb * 4 + nb] = __builtin_amdgcn_mfma_f32_16x16x32_f16(
                            al[mb], bh[nb], accL[mb * 4 + nb], 0, 0, 0);
            }
    }

    // epilogue: v = accH + accL/2048 + bias, relu. C/D: col(co)=lane&15, row(px)=q*4+reg
    const float inv2048 = 1.0f / 2048.0f;
    float bv[4];
#pragma unroll
    for (int nb = 0; nb < 4; ++nb) bv[nb] = bias[ch * 64 + nb * 16 + l15];
#pragma unroll
    for (int mb = 0; mb < 4; ++mb) {
#pragma unroll
        for (int r = 0; r < 4; ++r) {
            int m = ph * 64 + mb * 16 + q * 4 + r;
            int img = m >> 6, px = m & 63;
            long base = ((long)(n0 + img) * 64 + px) * 128;
#pragma unroll
            for (int nb = 0; nb < 4; ++nb) {
                float v = accH[mb * 4 + nb][r] + accL[mb * 4 + nb][r] * inv2048 + bv[nb];
                v = fmaxf(v, 0.0f);
                int co = ch * 64 + nb * 16 + l15;
                if constexpr (OUTF32) {
                    ((float*)outv)[base + co] = v;
                } else {
                    ((unsigned int*)outv)[base + co] = splitpack(v);
                }
            }
        }
    }
}

// GAP over NHWC fp32 [n][64][128] -> feat [n][128]
__global__ void gap_nhwc(const float* __restrict__ in, float* __restrict__ out) {
    int n = blockIdx.x;
    int c = threadIdx.x;
    const float* p = in + (long)n * 8192 + c;
    float s = 0.0f;
#pragma unroll
    for (int px = 0; px < 64; ++px) s += p[px * 128];
    out[n * 128 + c] = s * (1.0f / 64.0f);
}

// ---------------------------------------------------------------------------
__global__ void trunk_pool(const float* __restrict__ in, float* __restrict__ out) {
    int g = blockIdx.x * 256 + threadIdx.x;
    if (g >= B_ * 128) return;
    int n = g >> 7;
    int r = g & 127;
    int c = r >> 2;
    int i = (r >> 1) & 1;
    int j = r & 1;
    const float* p = in + ((long)n * 32 + c) * 256 + i * 8 * 16 + j * 8;
    float s = 0.0f;
#pragma unroll
    for (int y = 0; y < 8; ++y)
#pragma unroll
        for (int x = 0; x < 8; ++x) s += p[y * 16 + x];
    out[g] = s * (1.0f / 64.0f);
}

template <int I, int O, bool RELU>
__global__ void fc_k(const float* __restrict__ in, const float* __restrict__ W,
                     const float* __restrict__ bias, float* __restrict__ out) {
    int g = blockIdx.x * 256 + threadIdx.x;
    if (g >= B_ * O) return;
    int n = g / O;
    int o = g - n * O;
    const float* ip = in + (long)n * I;
    const float* wp = W + (long)o * I;
    float a = bias[o];
#pragma unroll 8
    for (int k = 0; k < I; ++k) a = fmaf(ip[k], wp[k], a);
    if (RELU) a = fmaxf(a, 0.0f);
    out[g] = a;
}

__global__ void conf_bal_k(const float* __restrict__ logitsE, const float* __restrict__ gate,
                           const float* __restrict__ ema, float* __restrict__ balanced) {
    int g = blockIdx.x * 256 + threadIdx.x;
    if (g >= B_ * E_) return;
    int b = g / E_;
    int e = g - b * E_;
    const float* lp = logitsE + ((long)e * B_ + b) * 10;
    float m = lp[0];
#pragma unroll
    for (int k = 1; k < 10; ++k) m = fmaxf(m, lp[k]);
    float s = 0.0f;
#pragma unroll
    for (int k = 0; k < 10; ++k) s += expf(lp[k] - m);
    float ls = m + logf(s);
    float conf = 0.0f;
#pragma unroll
    for (int k = 0; k < 10; ++k) {
        float p = expf(lp[k] - ls);
        conf += p * logf(p + 1e-12f);
    }
    float em = ema[e];
    float boost = (em < 0.05f) ? (0.05f - em) * 10.0f : 0.0f;
    float comb = 0.7f * gate[b * E_ + e] + 0.3f * conf + boost;
    balanced[g] = comb - 2.0f * em;
}

__device__ __forceinline__ float load_sel(int i, float l0, float l1, float l2, float l3,
                                          float l4, float l5) {
    float r = l0;
    r = (i == 1) ? l1 : r;
    r = (i == 2) ? l2 : r;
    r = (i == 3) ? l3 : r;
    r = (i == 4) ? l4 : r;
    r = (i == 5) ? l5 : r;
    return r;
}

__global__ void dispatch_k(const float* __restrict__ balanced, int* __restrict__ chosen) {
    int lane = threadIdx.x;
    int t0[16], t1[16], ch[16];
#pragma unroll
    for (int r = 0; r < 16; ++r) {
        int b = r * 64 + lane;
        const float* bp = balanced + b * E_;
        float v[E_];
#pragma unroll
        for (int e = 0; e < E_; ++e) v[e] = bp[e];
        int i0 = 0;
        float m0 = v[0];
#pragma unroll
        for (int e = 1; e < E_; ++e)
            if (v[e] > m0) { m0 = v[e]; i0 = e; }
        int i1 = -1;
        float m1 = -1e38f;
#pragma unroll
        for (int e = 0; e < E_; ++e)
            if (e != i0 && v[e] > m1) { m1 = v[e]; i1 = e; }
        t0[r] = i0;
        t1[r] = i1;
    }
    float l0 = 0, l1 = 0, l2 = 0, l3 = 0, l4 = 0, l5 = 0;
#pragma unroll
    for (int r = 0; r < 16; ++r) {
        for (int q = 0; q < 64; ++q) {
            int i0 = __shfl(t0[r], q);
            int i1 = __shfl(t1[r], q);
            float a0 = load_sel(i0, l0, l1, l2, l3, l4, l5);
            float a1 = load_sel(i1, l0, l1, l2, l3, l4, l5);
            bool f0 = a0 < CAPF;
            bool f1 = a1 < CAPF;
            int fb = (a1 < a0) ? i1 : i0;
            int c = f0 ? i0 : (f1 ? i1 : fb);
            if (lane == q) ch[r] = c;
            l0 += (c == 0) ? 1.0f : 0.0f;
            l1 += (c == 1) ? 1.0f : 0.0f;
            l2 += (c == 2) ? 1.0f : 0.0f;
            l3 += (c == 3) ? 1.0f : 0.0f;
            l4 += (c == 4) ? 1.0f : 0.0f;
            l5 += (c == 5) ? 1.0f : 0.0f;
        }
    }
#pragma unroll
    for (int r = 0; r < 16; ++r) chosen[r * 64 + lane] = ch[r];
}

__global__ void final_k(const float* __restrict__ logitsE, const int* __restrict__ chosen,
                        float* __restrict__ out) {
    int b = blockIdx.x * 256 + threadIdx.x;
    if (b >= B_) return;
    int c = chosen[b];
    const float w = 1.0f / (1.0f + 1e-12f);
    const float* lp = logitsE + ((long)c * B_ + b) * 10;
#pragma unroll
    for (int k = 0; k < 10; ++k) out[b * 10 + k] = lp[k] * w;
    float* Dp = out + B_ * 10 + B_ * E_ + b * E_;
#pragma unroll
    for (int e = 0; e < E_; ++e) Dp[e] = (e == c) ? 1.0f : 0.0f;
}

// ---------------------------------------------------------------------------
extern "C" void kernel_launch(void* const* d_in, const int* in_sizes, int n_in,
                              void* d_out, int out_size, void* d_ws, size_t ws_size,
                              hipStream_t stream) {
    (void)in_sizes; (void)n_in; (void)out_size; (void)ws_size;
    const float* x     = (const float*)d_in[0];
    const float* t_c1w = (const float*)d_in[1];
    const float* t_b1g = (const float*)d_in[2];
    const float* t_b1b = (const float*)d_in[3];
    const float* t_c2w = (const float*)d_in[4];
    const float* t_b2g = (const float*)d_in[5];
    const float* t_b2b = (const float*)d_in[6];
    const float* t_fcw = (const float*)d_in[7];
    const float* t_fcb = (const float*)d_in[8];
    const float* g1w   = (const float*)d_in[9];
    const float* g1b   = (const float*)d_in[10];
    const float* g2w   = (const float*)d_in[11];
    const float* g2b   = (const float*)d_in[12];
    const float* e_c1w = (const float*)d_in[13];
    const float* e_c1b = (const float*)d_in[14];
    const float* e_b1g = (const float*)d_in[15];
    const float* e_b1b = (const float*)d_in[16];
    const float* e_c2w = (const float*)d_in[17];
    const float* e_c2b = (const float*)d_in[18];
    const float* e_b2g = (const float*)d_in[19];
    const float* e_b2b = (const float*)d_in[20];
    const float* e_c3w = (const float*)d_in[21];
    const float* e_c3b = (const float*)d_in[22];
    const float* e_b3g = (const float*)d_in[23];
    const float* e_b3b = (const float*)d_in[24];
    const float* e_c4w = (const float*)d_in[25];
    const float* e_c4b = (const float*)d_in[26];
    const float* e_b4g = (const float*)d_in[27];
    const float* e_b4b = (const float*)d_in[28];
    const float* e_c5w = (const float*)d_in[29];
    const float* e_c5b = (const float*)d_in[30];
    const float* e_b5g = (const float*)d_in[31];
    const float* e_b5b = (const float*)d_in[32];
    const float* e_fw  = (const float*)d_in[33];
    const float* e_fb  = (const float*)d_in[34];
    const float* e_cw  = (const float*)d_in[35];
    const float* e_cb  = (const float*)d_in[36];
    const float* ema   = (const float*)d_in[37];
    float* out = (float*)d_out;
    float* ws  = (float*)d_ws;

    // workspace layout (float slots)
    size_t o = 0;
    float* bufA    = ws + o; o += 16777216;   // 64 MB
    float* bufB    = ws + o; o += 8388608;    // 32 MB
    float* rf_in   = ws + o; o += B_ * 128;
    float* rf      = ws + o; o += B_ * 64;
    float* gv      = ws + o; o += B_ * 32;
    float* gate    = ws + o; o += B_ * E_;
    float* logitsE = ws + o; o += E_ * B_ * 10;
    float* feat    = ws + o; o += B_ * 128;
    float* fv      = ws + o; o += B_ * 128;
    int*   chosen  = (int*)(ws + o); o += B_;
    float* wt_t1 = ws + o; o += 864;
    float* bt_t1 = ws + o; o += 32;
    float* wt_t2 = ws + o; o += 9216;
    float* bt_t2 = ws + o; o += 32;
    float* wt_c1 = ws + o; o += 6 * 864;
    float* bt_c1 = ws + o; o += 6 * 32;
    float* wt_c2 = ws + o; o += 6 * 18432;
    float* bt_c2 = ws + o; o += 6 * 64;
    float* wt_c3 = ws + o; o += 6 * 36864;
    float* bt_c3 = ws + o; o += 6 * 64;
    _Float16* wfrag_c4 = (_Float16*)(ws + o); o += 442368;   // 6*147456 f16
    _Float16* wfrag_c5 = (_Float16*)(ws + o); o += 884736;   // 6*294912 f16
    float* bt_c4 = ws + o; o += 6 * 128;
    float* bt_c5 = ws + o; o += 6 * 128;

    auto gsz = [](int n) { return (n + 255) / 256; };
    // ---- weight prep ----
    prep_w<<<gsz(864), 256, 0, stream>>>(t_c1w, t_b1g, wt_t1, 32, 3, 864);
    prep_b<<<1, 256, 0, stream>>>(nullptr, t_b1g, t_b1b, bt_t1, 32);
    prep_w<<<gsz(9216), 256, 0, stream>>>(t_c2w, t_b2g, wt_t2, 32, 32, 9216);
    prep_b<<<1, 256, 0, stream>>>(nullptr, t_b2g, t_b2b, bt_t2, 32);
    prep_w<<<gsz(5184), 256, 0, stream>>>(e_c1w, e_b1g, wt_c1, 32, 3, 5184);
    prep_b<<<1, 256, 0, stream>>>(e_c1b, e_b1g, e_b1b, bt_c1, 192);
    prep_w<<<gsz(110592), 256, 0, stream>>>(e_c2w, e_b2g, wt_c2, 64, 32, 110592);
    prep_b<<<2, 256, 0, stream>>>(e_c2b, e_b2g, e_b2b, bt_c2, 384);
    prep_w<<<gsz(221184), 256, 0, stream>>>(e_c3w, e_b3g, wt_c3, 64, 64, 221184);
    prep_b<<<2, 256, 0, stream>>>(e_c3b, e_b3g, e_b3b, bt_c3, 384);
    // thread count = 6*8*9*NC*512 (each thread writes hi AND lo planes)
    prep_wfrag<<<gsz(442368), 256, 0, stream>>>(e_c4w, e_b4g, wfrag_c4, 64, 442368);
    prep_b<<<3, 256, 0, stream>>>(e_c4b, e_b4g, e_b4b, bt_c4, 768);
    prep_wfrag<<<gsz(884736), 256, 0, stream>>>(e_c5w, e_b5g, wfrag_c5, 128, 884736);
    prep_b<<<3, 256, 0, stream>>>(e_c5b, e_b5g, e_b5b, bt_c5, 768);

    // ---- routing trunk (2 batch-halves) ----
    for (int q = 0; q < 2; ++q) {
        const float* xq = x + (size_t)q * 512 * 3 * 1024;
        conv3x3<3, 32, 32, 16, 32, 3, false><<<512 * 4, 256, 0, stream>>>(xq, wt_t1, bt_t1, bufA);
        conv3x3<32, 32, 32, 16, 8, 16, true><<<512 * 4, 256, 0, stream>>>(
            bufA, wt_t2, bt_t2, bufB + (size_t)q * 512 * 32 * 256);
    }
    trunk_pool<<<512, 256, 0, stream>>>(bufB, rf_in);
    fc_k<128, 64, true><<<256, 256, 0, stream>>>(rf_in, t_fcw, t_fcb, rf);
    fc_k<64, 32, true><<<128, 256, 0, stream>>>(rf, g1w, g1b, gv);
    fc_k<32, 6, false><<<24, 256, 0, stream>>>(gv, g2w, g2b, gate);

    // ---- experts ----
    unsigned int* c4in  = (unsigned int*)bufA;              // [1024][64][64] packed
    float*        c5out = bufA + 4194304;                   // [1024][64][128] fp32
    unsigned int* c5in  = (unsigned int*)bufB;              // [1024][64][128] packed
    for (int e = 0; e < E_; ++e) {
        conv3x3<3, 32, 32, 16, 8, 3, true><<<B_ * 4, 256, 0, stream>>>(
            x, wt_c1 + e * 864, bt_c1 + e * 32, bufB);
        conv3x3<32, 64, 16, 16, 32, 16, false><<<B_, 256, 0, stream>>>(
            bufB, wt_c2 + e * 18432, bt_c2 + e * 64, bufA);
        conv3x3<64, 64, 16, 16, 16, 16, true><<<B_, 256, 0, stream>>>(
            bufA, wt_c3 + e * 36864, bt_c3 + e * 64, bufB);
        repack_k<<<B_, 256, 0, stream>>>(bufB, c4in);
        conv_mfma<64, 0><<<512, 256, 0, stream>>>(
            c4in, wfrag_c4 + (size_t)e * 147456, bt_c4 + e * 128, (void*)c5in);
        conv_mfma<128, 1><<<512, 256, 0, stream>>>(
            c5in, wfrag_c5 + (size_t)e * 294912, bt_c5 + e * 128, (void*)c5out);
        gap_nhwc<<<B_, 128, 0, stream>>>(c5out, feat);
        fc_k<128, 128, true><<<512, 256, 0, stream>>>(feat, e_fw + e * 16384, e_fb + e * 128, fv);
        fc_k<128, 10, false><<<40, 256, 0, stream>>>(fv, e_cw + e * 1280, e_cb + e * 10,
                                                     logitsE + (size_t)e * B_ * 10);
    }

    // ---- scoring, dispatch, combine ----
    float* balanced = out + B_ * 10;
    conf_bal_k<<<24, 256, 0, stream>>>(logitsE, gate, ema, balanced);
    dispatch_k<<<1, 64, 0, stream>>>(balanced, chosen);
    final_k<<<4, 256, 0, stream>>>(logitsE, chosen, out);
}

// Round 5
// 2443.226 us; speedup vs baseline: 2.7818x; 1.4550x over previous
//
#include <hip/hip_runtime.h>
#include <math.h>

#define B_ 1024
#define E_ 6
#define CAPF 192.0f

typedef _Float16 half8 __attribute__((ext_vector_type(8)));
typedef float f32x4 __attribute__((ext_vector_type(4)));

__device__ __forceinline__ unsigned short h_bits(_Float16 h) {
    union { _Float16 f; unsigned short u; } c; c.f = h; return c.u;
}
// pack fp32 -> (hi fp16 | lo fp16<<16), lo prescaled by 2048 to avoid fp16 subnormals
__device__ __forceinline__ unsigned int splitpack(float v) {
    _Float16 h = (_Float16)v;
    _Float16 l = (_Float16)((v - (float)h) * 2048.0f);
    return (unsigned int)h_bits(h) | ((unsigned int)h_bits(l) << 16);
}

// ---------------------------------------------------------------------------
// Old-style weight prep (trunk + c1): fold BN, transpose to [ci][k][co].
// ---------------------------------------------------------------------------
__global__ void prep_w(const float* __restrict__ w, const float* __restrict__ g,
                       float* __restrict__ wout, int CO, int CI, int total) {
    int i = blockIdx.x * 256 + threadIdx.x;
    if (i >= total) return;
    int k = i % 9;
    int t = i / 9;
    int ci = t % CI; t /= CI;
    int co = t % CO;
    int e  = t / CO;
    float s = g[e * CO + co] * (1.0f / sqrtf(1.0f + 1e-5f));
    wout[(((long)(e * CI + ci) * 9 + k) * CO) + co] = w[i] * s;
}

__global__ void prep_b(const float* __restrict__ cb, const float* __restrict__ g,
                       const float* __restrict__ bb, float* __restrict__ bout, int N) {
    int i = blockIdx.x * 256 + threadIdx.x;
    if (i >= N) return;
    float s = g[i] * (1.0f / sqrtf(1.0f + 1e-5f));
    float c = (cb != nullptr) ? cb[i] : 0.0f;
    bout[i] = c * s + bb[i];
}

// ---------------------------------------------------------------------------
// Generic MFMA weight prep (c2..c5): fold BN, split fp16 hi/lo (lo*2048),
// store in B-fragment order: [e][nbg NB][tap 9][chunk NC][plane 2][lane 64][j 8].
// B[k][n]: n = lane&15 (co within 16-block), k = (lane>>4)*8+j (ci in chunk).
// total = E*NB*9*NC*512 threads; each thread writes BOTH hi and lo planes.
// ---------------------------------------------------------------------------
__global__ void prep_wfrag(const float* __restrict__ w, const float* __restrict__ g,
                           _Float16* __restrict__ out, int CI, int CO, int total) {
    int i = blockIdx.x * 256 + threadIdx.x;
    if (i >= total) return;
    const int NC = CI / 32;
    const int NB = CO / 16;
    int j = i & 7;
    int lane = (i >> 3) & 63;
    int rest = i >> 9;
    int chunk = rest % NC; rest /= NC;
    int tap = rest % 9; rest /= 9;
    int nbg = rest % NB;
    int e = rest / NB;
    int co = nbg * 16 + (lane & 15);
    int ci = chunk * 32 + ((lane >> 4) * 8) + j;
    float s = g[e * CO + co] * (1.0f / sqrtf(1.0f + 1e-5f));
    float v = w[(((long)(e * CO + co) * CI + ci) * 9) + tap] * s;
    _Float16 hi = (_Float16)v;
    _Float16 lo = (_Float16)((v - (float)hi) * 2048.0f);
    long perE = (long)NB * 9 * NC * 2 * 512;
    long F0 = ((long)(nbg * 9 + tap) * NC + chunk) * 2;
    long base = (long)e * perE + F0 * 512 + lane * 8 + j;
    out[base] = hi;
    out[base + 512] = lo;
}

// ---------------------------------------------------------------------------
// Direct conv (trunk t1/t2 + expert c1).
// ---------------------------------------------------------------------------
template <int CI, int CO, int H, int TS, int CO_BLK, int CI_CHUNK, bool POOL>
__launch_bounds__(256)
__global__ void conv3x3(const float* __restrict__ in, const float* __restrict__ wt,
                        const float* __restrict__ bias, float* __restrict__ out) {
    constexpr int TD = H / TS;
    constexpr int TILES = TD * TD;
    constexpr int LW = TS + 2;
    constexpr int NPX = POOL ? (TS / 2) * (TS / 2) : TS * TS;
    constexpr int G = 256 / NPX;
    constexpr int NG = CO / CO_BLK;
    constexpr int GPT = NG / G;
    constexpr int COT = GPT * CO_BLK;
    constexpr int NW = POOL ? 4 : 1;
    constexpr int OD = POOL ? TS / 2 : TS;

    __shared__ float lds[CI_CHUNK * LW * LW];

    int bid = blockIdx.x;
    int n = bid / TILES;
    int t = bid % TILES;
    int ty = (t / TD) * TS;
    int tx = (t % TD) * TS;
    int tid = threadIdx.x;
    int px = tid % NPX;
    int cg0 = tid / NPX;
    const int cg0s = __builtin_amdgcn_readfirstlane(cg0);
    int oy = px / OD;
    int ox = px % OD;

    float acc[NW][COT];
#pragma unroll
    for (int g2 = 0; g2 < GPT; ++g2)
#pragma unroll
        for (int j = 0; j < CO_BLK; ++j) {
            float bv = bias[(cg0s + g2 * G) * CO_BLK + j];
#pragma unroll
            for (int p = 0; p < NW; ++p) acc[p][g2 * CO_BLK + j] = bv;
        }

    for (int cc = 0; cc < CI / CI_CHUNK; ++cc) {
        const float* inb = in + ((long)n * CI + cc * CI_CHUNK) * (H * H);
        for (int idx = tid; idx < CI_CHUNK * LW * LW; idx += 256) {
            int ci = idx / (LW * LW);
            int r = idx - ci * (LW * LW);
            int yy = r / LW + ty - 1;
            int xx = r % LW + tx - 1;
            float v = 0.0f;
            if ((unsigned)yy < (unsigned)H && (unsigned)xx < (unsigned)H)
                v = inb[ci * H * H + yy * H + xx];
            lds[idx] = v;
        }
        __syncthreads();

        const float* wbase = wt + ((long)cc * CI_CHUNK) * 9 * CO;
        for (int ci = 0; ci < CI_CHUNK; ++ci) {
#pragma unroll
            for (int ky = 0; ky < 3; ++ky) {
#pragma unroll
                for (int kx = 0; kx < 3; ++kx) {
                    float v[NW];
                    if constexpr (POOL) {
#pragma unroll
                        for (int dy = 0; dy < 2; ++dy)
#pragma unroll
                            for (int dx = 0; dx < 2; ++dx)
                                v[dy * 2 + dx] =
                                    lds[ci * LW * LW + (2 * oy + dy + ky) * LW + (2 * ox + dx + kx)];
                    } else {
                        v[0] = lds[ci * LW * LW + (oy + ky) * LW + (ox + kx)];
                    }
                    const float* wr = wbase + ((ci * 3 + ky) * 3 + kx) * CO + cg0s * CO_BLK;
#pragma unroll
                    for (int g2 = 0; g2 < GPT; ++g2)
#pragma unroll
                        for (int j = 0; j < CO_BLK; ++j) {
                            float wv = wr[g2 * G * CO_BLK + j];
#pragma unroll
                            for (int p = 0; p < NW; ++p)
                                acc[p][g2 * CO_BLK + j] = fmaf(v[p], wv, acc[p][g2 * CO_BLK + j]);
                        }
                }
            }
        }
        __syncthreads();
    }

    if constexpr (POOL) {
        constexpr int HP = H / 2;
        int py = ty / 2 + oy;
        int pxx = tx / 2 + ox;
#pragma unroll
        for (int g2 = 0; g2 < GPT; ++g2)
#pragma unroll
            for (int j = 0; j < CO_BLK; ++j) {
                int co = (cg0s + g2 * G) * CO_BLK + j;
                int a = g2 * CO_BLK + j;
                float m = fmaxf(fmaxf(acc[0][a], acc[1][a]), fmaxf(acc[2][a], acc[3][a]));
                out[((long)n * CO + co) * (HP * HP) + py * HP + pxx] = fmaxf(m, 0.0f);
            }
    } else {
        int yy = ty + oy;
        int xx = tx + ox;
#pragma unroll
        for (int g2 = 0; g2 < GPT; ++g2)
#pragma unroll
            for (int j = 0; j < CO_BLK; ++j) {
                int co = (cg0s + g2 * G) * CO_BLK + j;
                out[((long)n * CO + co) * (H * H) + yy * H + xx] =
                    fmaxf(acc[0][g2 * CO_BLK + j], 0.0f);
            }
    }
}

// ---------------------------------------------------------------------------
// Repack c1 output: NCHW fp32 [n][32][16][16] -> NHWC packed pair dwords
// [n][256][32]. LDS transpose, coalesced both sides.
// ---------------------------------------------------------------------------
__global__ void repack16(const float* __restrict__ in, unsigned int* __restrict__ out) {
    __shared__ float t[256 * 33];
    int n = blockIdx.x;
    const float* ip = in + (long)n * 8192;
    for (int u = threadIdx.x; u < 8192; u += 256) {
        int px = u & 255, c = u >> 8;
        t[px * 33 + c] = ip[u];
    }
    __syncthreads();
    for (int u = threadIdx.x; u < 8192; u += 256) {
        int c = u & 31, px = u >> 5;
        out[(long)n * 8192 + u] = splitpack(t[px * 33 + c]);
    }
}

// ---------------------------------------------------------------------------
// MFMA conv 3x3 on 16x16 spatial, split-fp16, CO=64.  One image per block,
// 4 waves; wave wv owns y-rows wv*4..wv*4+3 (4 m-blocks) x all 64 co (4
// n-blocks).  POOL fuses 2x2 maxpool entirely in registers (x-pairs = reg
// pairs r=2j,2j+1; y-pairs = m-block pairs) and emits [n][64][64] packed
// (exactly the c4 NHWC input).  Non-POOL emits [n][256][64] packed.
// ---------------------------------------------------------------------------
template <int CI, bool POOL>
__launch_bounds__(256, 2)
__global__ void conv_mfma16(const unsigned int* __restrict__ in,
                            const _Float16* __restrict__ wt,
                            const float* __restrict__ bias,
                            unsigned int* __restrict__ outp) {
    constexpr int NC = CI / 32;
    constexpr int PXS = 40;  // LDS pixel stride (32 payload + 8 pad) f16
    __shared__ _Float16 ldsH[18 * 18 * PXS];
    __shared__ _Float16 ldsL[18 * 18 * PXS];

    const int tid = threadIdx.x;
    const int wv = tid >> 6, lane = tid & 63;
    const int q = lane >> 4, l15 = lane & 15;
    const int n = blockIdx.x;

    {
        half8 z = {};
        half8* zh = (half8*)ldsH;
        half8* zl = (half8*)ldsL;
        for (int i = tid; i < 18 * 18 * PXS / 8; i += 256) { zh[i] = z; zl[i] = z; }
    }

    f32x4 accH[16], accL[16];
#pragma unroll
    for (int i = 0; i < 16; ++i) { accH[i] = (f32x4){0,0,0,0}; accL[i] = (f32x4){0,0,0,0}; }

    for (int c = 0; c < NC; ++c) {
        __syncthreads();
        // stage 256 px x 8 ci-quads of this chunk
        for (int v = tid; v < 2048; v += 256) {
            int cu = v & 7;
            int px = v >> 3;
            long gidx = ((long)n * 256 + px) * CI + c * 32 + cu * 4;
            uint4 w = *(const uint4*)(in + gidx);
            unsigned int h01 = (w.x & 0xffffu) | (w.y << 16);
            unsigned int h23 = (w.z & 0xffffu) | (w.w << 16);
            unsigned int l01 = (w.x >> 16) | (w.y & 0xffff0000u);
            unsigned int l23 = (w.z >> 16) | (w.w & 0xffff0000u);
            int py = px >> 4, pxx = px & 15;
            int fi = ((py + 1) * 18 + (pxx + 1)) * PXS + cu * 4;
            *(uint2*)(&ldsH[fi]) = make_uint2(h01, h23);
            *(uint2*)(&ldsL[fi]) = make_uint2(l01, l23);
        }
        __syncthreads();

#pragma unroll
        for (int ky = 0; ky < 3; ++ky)
#pragma unroll
            for (int kx = 0; kx < 3; ++kx) {
                const int tap = ky * 3 + kx;
                half8 ah[4], al[4];
#pragma unroll
                for (int mb = 0; mb < 4; ++mb) {
                    int y = wv * 4 + mb;
                    int fi = ((y + ky) * 18 + (l15 + kx)) * PXS + q * 8;
                    ah[mb] = *(const half8*)&ldsH[fi];
                    al[mb] = *(const half8*)&ldsL[fi];
                }
                half8 bh[4], bl[4];
#pragma unroll
                for (int nb = 0; nb < 4; ++nb) {
                    int F0 = ((nb * 9 + tap) * NC + c) * 2;
                    bh[nb] = ((const half8*)wt)[(long)F0 * 64 + lane];
                    bl[nb] = ((const half8*)wt)[(long)(F0 + 1) * 64 + lane];
                }
#pragma unroll
                for (int nb = 0; nb < 4; ++nb)
#pragma unroll
                    for (int mb = 0; mb < 4; ++mb)
                        accH[mb * 4 + nb] = __builtin_amdgcn_mfma_f32_16x16x32_f16(
                            ah[mb], bh[nb], accH[mb * 4 + nb], 0, 0, 0);
#pragma unroll
                for (int nb = 0; nb < 4; ++nb)
#pragma unroll
                    for (int mb = 0; mb < 4; ++mb)
                        accL[mb * 4 + nb] = __builtin_amdgcn_mfma_f32_16x16x32_f16(
                            ah[mb], bl[nb], accL[mb * 4 + nb], 0, 0, 0);
#pragma unroll
                for (int nb = 0; nb < 4; ++nb)
#pragma unroll
                    for (int mb = 0; mb < 4; ++mb)
                        accL[mb * 4 + nb] = __builtin_amdgcn_mfma_f32_16x16x32_f16(
                            al[mb], bh[nb], accL[mb * 4 + nb], 0, 0, 0);
            }
    }

    // epilogue.  D layout: col(co)=lane&15, row(x)=q*4+reg; m-block = y row.
    const float inv2048 = 1.0f / 2048.0f;
    float bv[4];
#pragma unroll
    for (int nb = 0; nb < 4; ++nb) bv[nb] = bias[nb * 16 + l15];

    if constexpr (POOL) {
#pragma unroll
        for (int k = 0; k < 2; ++k) {
#pragma unroll
            for (int j = 0; j < 2; ++j) {
                int yy = wv * 2 + k;
                int xx = q * 2 + j;
                long base = ((long)n * 64 + yy * 8 + xx) * 64;
#pragma unroll
                for (int nb = 0; nb < 4; ++nb) {
                    float m = -1e30f;
#pragma unroll
                    for (int dm = 0; dm < 2; ++dm)
#pragma unroll
                        for (int dr = 0; dr < 2; ++dr) {
                            int a = (2 * k + dm) * 4 + nb;
                            int r = 2 * j + dr;
                            float v = accH[a][r] + accL[a][r] * inv2048 + bv[nb];
                            m = fmaxf(m, v);
                        }
                    m = fmaxf(m, 0.0f);
                    outp[base + nb * 16 + l15] = splitpack(m);
                }
            }
        }
    } else {
#pragma unroll
        for (int mb = 0; mb < 4; ++mb) {
            int y = wv * 4 + mb;
#pragma unroll
            for (int r = 0; r < 4; ++r) {
                int px = y * 16 + q * 4 + r;
                long base = ((long)n * 256 + px) * 64;
#pragma unroll
                for (int nb = 0; nb < 4; ++nb) {
                    float v = accH[mb * 4 + nb][r] + accL[mb * 4 + nb][r] * inv2048 + bv[nb];
                    v = fmaxf(v, 0.0f);
                    outp[base + nb * 16 + l15] = splitpack(v);
                }
            }
        }
    }
}

// ---------------------------------------------------------------------------
// MFMA conv 3x3 on 8x8 spatial (c4/c5), split-fp16, CO=128.  2 images/block.
// ---------------------------------------------------------------------------
template <int CI, int OUTF32>
__launch_bounds__(256, 2)
__global__ void conv_mfma(const unsigned int* __restrict__ in,
                          const _Float16* __restrict__ wt,
                          const float* __restrict__ bias, void* __restrict__ outv) {
    constexpr int NC = CI / 32;
    constexpr int PXS = 40;
    __shared__ _Float16 ldsH[2 * 100 * PXS];
    __shared__ _Float16 ldsL[2 * 100 * PXS];

    const int tid = threadIdx.x;
    const int wv = tid >> 6, lane = tid & 63;
    const int ph = wv & 1, ch = wv >> 1;
    const int q = lane >> 4, l15 = lane & 15;
    const int n0 = blockIdx.x * 2;

    {
        half8 z = {};
        half8* zh = (half8*)ldsH;
        half8* zl = (half8*)ldsL;
        for (int i = tid; i < 2 * 100 * PXS / 8; i += 256) { zh[i] = z; zl[i] = z; }
    }

    f32x4 accH[16], accL[16];
#pragma unroll
    for (int i = 0; i < 16; ++i) { accH[i] = (f32x4){0,0,0,0}; accL[i] = (f32x4){0,0,0,0}; }

    for (int c = 0; c < NC; ++c) {
        __syncthreads();
        for (int u = tid; u < 1024; u += 256) {
            int cu = u & 7;
            int px = (u >> 3) & 63;
            int img = u >> 9;
            long gidx = ((long)(n0 + img) * 64 + px) * CI + c * 32 + cu * 4;
            uint4 w = *(const uint4*)(in + gidx);
            unsigned int h01 = (w.x & 0xffffu) | (w.y << 16);
            unsigned int h23 = (w.z & 0xffffu) | (w.w << 16);
            unsigned int l01 = (w.x >> 16) | (w.y & 0xffff0000u);
            unsigned int l23 = (w.z >> 16) | (w.w & 0xffff0000u);
            int py = px >> 3, pxx = px & 7;
            int fi = (img * 100 + (py + 1) * 10 + (pxx + 1)) * PXS + cu * 4;
            *(uint2*)(&ldsH[fi]) = make_uint2(h01, h23);
            *(uint2*)(&ldsL[fi]) = make_uint2(l01, l23);
        }
        __syncthreads();

#pragma unroll
        for (int ky = 0; ky < 3; ++ky)
#pragma unroll
            for (int kx = 0; kx < 3; ++kx) {
                const int tap = ky * 3 + kx;
                half8 ah[4], al[4];
#pragma unroll
                for (int mb = 0; mb < 4; ++mb) {
                    int m = ph * 64 + mb * 16 + l15;
                    int img = m >> 6, py = (m >> 3) & 7, pxx = m & 7;
                    int fi = (img * 100 + (py + ky) * 10 + (pxx + kx)) * PXS + q * 8;
                    ah[mb] = *(const half8*)&ldsH[fi];
                    al[mb] = *(const half8*)&ldsL[fi];
                }
                half8 bh[4], bl[4];
#pragma unroll
                for (int nb = 0; nb < 4; ++nb) {
                    int nbg = ch * 4 + nb;
                    int F0 = ((nbg * 9 + tap) * NC + c) * 2;
                    bh[nb] = ((const half8*)wt)[(long)F0 * 64 + lane];
                    bl[nb] = ((const half8*)wt)[(long)(F0 + 1) * 64 + lane];
                }
#pragma unroll
                for (int nb = 0; nb < 4; ++nb)
#pragma unroll
                    for (int mb = 0; mb < 4; ++mb)
                        accH[mb * 4 + nb] = __builtin_amdgcn_mfma_f32_16x16x32_f16(
                            ah[mb], bh[nb], accH[mb * 4 + nb], 0, 0, 0);
#pragma unroll
                for (int nb = 0; nb < 4; ++nb)
#pragma unroll
                    for (int mb = 0; mb < 4; ++mb)
                        accL[mb * 4 + nb] = __builtin_amdgcn_mfma_f32_16x16x32_f16(
                            ah[mb], bl[nb], accL[mb * 4 + nb], 0, 0, 0);
#pragma unroll
                for (int nb = 0; nb < 4; ++nb)
#pragma unroll
                    for (int mb = 0; mb < 4; ++mb)
                        accL[mb * 4 + nb] = __builtin_amdgcn_mfma_f32_16x16x32_f16(
                            al[mb], bh[nb], accL[mb * 4 + nb], 0, 0, 0);
            }
    }

    const float inv2048 = 1.0f / 2048.0f;
    float bv[4];
#pragma unroll
    for (int nb = 0; nb < 4; ++nb) bv[nb] = bias[ch * 64 + nb * 16 + l15];
#pragma unroll
    for (int mb = 0; mb < 4; ++mb) {
#pragma unroll
        for (int r = 0; r < 4; ++r) {
            int m = ph * 64 + mb * 16 + q * 4 + r;
            int img = m >> 6, px = m & 63;
            long base = ((long)(n0 + img) * 64 + px) * 128;
#pragma unroll
            for (int nb = 0; nb < 4; ++nb) {
                float v = accH[mb * 4 + nb][r] + accL[mb * 4 + nb][r] * inv2048 + bv[nb];
                v = fmaxf(v, 0.0f);
                int co = ch * 64 + nb * 16 + l15;
                if constexpr (OUTF32) {
                    ((float*)outv)[base + co] = v;
                } else {
                    ((unsigned int*)outv)[base + co] = splitpack(v);
                }
            }
        }
    }
}

// GAP over NHWC fp32 [n][64][128] -> feat [n][128]
__global__ void gap_nhwc(const float* __restrict__ in, float* __restrict__ out) {
    int n = blockIdx.x;
    int c = threadIdx.x;
    const float* p = in + (long)n * 8192 + c;
    float s = 0.0f;
#pragma unroll
    for (int px = 0; px < 64; ++px) s += p[px * 128];
    out[n * 128 + c] = s * (1.0f / 64.0f);
}

// ---------------------------------------------------------------------------
__global__ void trunk_pool(const float* __restrict__ in, float* __restrict__ out) {
    int g = blockIdx.x * 256 + threadIdx.x;
    if (g >= B_ * 128) return;
    int n = g >> 7;
    int r = g & 127;
    int c = r >> 2;
    int i = (r >> 1) & 1;
    int j = r & 1;
    const float* p = in + ((long)n * 32 + c) * 256 + i * 8 * 16 + j * 8;
    float s = 0.0f;
#pragma unroll
    for (int y = 0; y < 8; ++y)
#pragma unroll
        for (int x = 0; x < 8; ++x) s += p[y * 16 + x];
    out[g] = s * (1.0f / 64.0f);
}

template <int I, int O, bool RELU>
__global__ void fc_k(const float* __restrict__ in, const float* __restrict__ W,
                     const float* __restrict__ bias, float* __restrict__ out) {
    int g = blockIdx.x * 256 + threadIdx.x;
    if (g >= B_ * O) return;
    int n = g / O;
    int o = g - n * O;
    const float* ip = in + (long)n * I;
    const float* wp = W + (long)o * I;
    float a = bias[o];
#pragma unroll 8
    for (int k = 0; k < I; ++k) a = fmaf(ip[k], wp[k], a);
    if (RELU) a = fmaxf(a, 0.0f);
    out[g] = a;
}

__global__ void conf_bal_k(const float* __restrict__ logitsE, const float* __restrict__ gate,
                           const float* __restrict__ ema, float* __restrict__ balanced) {
    int g = blockIdx.x * 256 + threadIdx.x;
    if (g >= B_ * E_) return;
    int b = g / E_;
    int e = g - b * E_;
    const float* lp = logitsE + ((long)e * B_ + b) * 10;
    float m = lp[0];
#pragma unroll
    for (int k = 1; k < 10; ++k) m = fmaxf(m, lp[k]);
    float s = 0.0f;
#pragma unroll
    for (int k = 0; k < 10; ++k) s += expf(lp[k] - m);
    float ls = m + logf(s);
    float conf = 0.0f;
#pragma unroll
    for (int k = 0; k < 10; ++k) {
        float p = expf(lp[k] - ls);
        conf += p * logf(p + 1e-12f);
    }
    float em = ema[e];
    float boost = (em < 0.05f) ? (0.05f - em) * 10.0f : 0.0f;
    float comb = 0.7f * gate[b * E_ + e] + 0.3f * conf + boost;
    balanced[g] = comb - 2.0f * em;
}

__device__ __forceinline__ float load_sel(int i, float l0, float l1, float l2, float l3,
                                          float l4, float l5) {
    float r = l0;
    r = (i == 1) ? l1 : r;
    r = (i == 2) ? l2 : r;
    r = (i == 3) ? l3 : r;
    r = (i == 4) ? l4 : r;
    r = (i == 5) ? l5 : r;
    return r;
}

__global__ void dispatch_k(const float* __restrict__ balanced, int* __restrict__ chosen) {
    int lane = threadIdx.x;
    int t0[16], t1[16], ch[16];
#pragma unroll
    for (int r = 0; r < 16; ++r) {
        int b = r * 64 + lane;
        const float* bp = balanced + b * E_;
        float v[E_];
#pragma unroll
        for (int e = 0; e < E_; ++e) v[e] = bp[e];
        int i0 = 0;
        float m0 = v[0];
#pragma unroll
        for (int e = 1; e < E_; ++e)
            if (v[e] > m0) { m0 = v[e]; i0 = e; }
        int i1 = -1;
        float m1 = -1e38f;
#pragma unroll
        for (int e = 0; e < E_; ++e)
            if (e != i0 && v[e] > m1) { m1 = v[e]; i1 = e; }
        t0[r] = i0;
        t1[r] = i1;
    }
    float l0 = 0, l1 = 0, l2 = 0, l3 = 0, l4 = 0, l5 = 0;
#pragma unroll
    for (int r = 0; r < 16; ++r) {
        for (int q = 0; q < 64; ++q) {
            int i0 = __shfl(t0[r], q);
            int i1 = __shfl(t1[r], q);
            float a0 = load_sel(i0, l0, l1, l2, l3, l4, l5);
            float a1 = load_sel(i1, l0, l1, l2, l3, l4, l5);
            bool f0 = a0 < CAPF;
            bool f1 = a1 < CAPF;
            int fb = (a1 < a0) ? i1 : i0;
            int c = f0 ? i0 : (f1 ? i1 : fb);
            if (lane == q) ch[r] = c;
            l0 += (c == 0) ? 1.0f : 0.0f;
            l1 += (c == 1) ? 1.0f : 0.0f;
            l2 += (c == 2) ? 1.0f : 0.0f;
            l3 += (c == 3) ? 1.0f : 0.0f;
            l4 += (c == 4) ? 1.0f : 0.0f;
            l5 += (c == 5) ? 1.0f : 0.0f;
        }
    }
#pragma unroll
    for (int r = 0; r < 16; ++r) chosen[r * 64 + lane] = ch[r];
}

__global__ void final_k(const float* __restrict__ logitsE, const int* __restrict__ chosen,
                        float* __restrict__ out) {
    int b = blockIdx.x * 256 + threadIdx.x;
    if (b >= B_) return;
    int c = chosen[b];
    const float w = 1.0f / (1.0f + 1e-12f);
    const float* lp = logitsE + ((long)c * B_ + b) * 10;
#pragma unroll
    for (int k = 0; k < 10; ++k) out[b * 10 + k] = lp[k] * w;
    float* Dp = out + B_ * 10 + B_ * E_ + b * E_;
#pragma unroll
    for (int e = 0; e < E_; ++e) Dp[e] = (e == c) ? 1.0f : 0.0f;
}

// ---------------------------------------------------------------------------
extern "C" void kernel_launch(void* const* d_in, const int* in_sizes, int n_in,
                              void* d_out, int out_size, void* d_ws, size_t ws_size,
                              hipStream_t stream) {
    (void)in_sizes; (void)n_in; (void)out_size; (void)ws_size;
    const float* x     = (const float*)d_in[0];
    const float* t_c1w = (const float*)d_in[1];
    const float* t_b1g = (const float*)d_in[2];
    const float* t_b1b = (const float*)d_in[3];
    const float* t_c2w = (const float*)d_in[4];
    const float* t_b2g = (const float*)d_in[5];
    const float* t_b2b = (const float*)d_in[6];
    const float* t_fcw = (const float*)d_in[7];
    const float* t_fcb = (const float*)d_in[8];
    const float* g1w   = (const float*)d_in[9];
    const float* g1b   = (const float*)d_in[10];
    const float* g2w   = (const float*)d_in[11];
    const float* g2b   = (const float*)d_in[12];
    const float* e_c1w = (const float*)d_in[13];
    const float* e_c1b = (const float*)d_in[14];
    const float* e_b1g = (const float*)d_in[15];
    const float* e_b1b = (const float*)d_in[16];
    const float* e_c2w = (const float*)d_in[17];
    const float* e_c2b = (const float*)d_in[18];
    const float* e_b2g = (const float*)d_in[19];
    const float* e_b2b = (const float*)d_in[20];
    const float* e_c3w = (const float*)d_in[21];
    const float* e_c3b = (const float*)d_in[22];
    const float* e_b3g = (const float*)d_in[23];
    const float* e_b3b = (const float*)d_in[24];
    const float* e_c4w = (const float*)d_in[25];
    const float* e_c4b = (const float*)d_in[26];
    const float* e_b4g = (const float*)d_in[27];
    const float* e_b4b = (const float*)d_in[28];
    const float* e_c5w = (const float*)d_in[29];
    const float* e_c5b = (const float*)d_in[30];
    const float* e_b5g = (const float*)d_in[31];
    const float* e_b5b = (const float*)d_in[32];
    const float* e_fw  = (const float*)d_in[33];
    const float* e_fb  = (const float*)d_in[34];
    const float* e_cw  = (const float*)d_in[35];
    const float* e_cb  = (const float*)d_in[36];
    const float* ema   = (const float*)d_in[37];
    float* out = (float*)d_out;
    float* ws  = (float*)d_ws;

    // workspace layout (float slots)
    size_t o = 0;
    float* bufA    = ws + o; o += 16777216;   // 64 MB
    float* bufB    = ws + o; o += 8388608;    // 32 MB
    float* rf_in   = ws + o; o += B_ * 128;
    float* rf      = ws + o; o += B_ * 64;
    float* gv      = ws + o; o += B_ * 32;
    float* gate    = ws + o; o += B_ * E_;
    float* logitsE = ws + o; o += E_ * B_ * 10;
    float* feat    = ws + o; o += B_ * 128;
    float* fv      = ws + o; o += B_ * 128;
    int*   chosen  = (int*)(ws + o); o += B_;
    float* wt_t1 = ws + o; o += 864;
    float* bt_t1 = ws + o; o += 32;
    float* wt_t2 = ws + o; o += 9216;
    float* bt_t2 = ws + o; o += 32;
    float* wt_c1 = ws + o; o += 6 * 864;
    float* bt_c1 = ws + o; o += 6 * 32;
    _Float16* wfrag_c2 = (_Float16*)(ws + o); o += 110592;   // 6*36864 f16
    _Float16* wfrag_c3 = (_Float16*)(ws + o); o += 221184;   // 6*73728 f16
    _Float16* wfrag_c4 = (_Float16*)(ws + o); o += 442368;   // 6*147456 f16
    _Float16* wfrag_c5 = (_Float16*)(ws + o); o += 884736;   // 6*294912 f16
    float* bt_c2 = ws + o; o += 6 * 64;
    float* bt_c3 = ws + o; o += 6 * 64;
    float* bt_c4 = ws + o; o += 6 * 128;
    float* bt_c5 = ws + o; o += 6 * 128;

    auto gsz = [](int n) { return (n + 255) / 256; };
    // ---- weight prep ----
    prep_w<<<gsz(864), 256, 0, stream>>>(t_c1w, t_b1g, wt_t1, 32, 3, 864);
    prep_b<<<1, 256, 0, stream>>>(nullptr, t_b1g, t_b1b, bt_t1, 32);
    prep_w<<<gsz(9216), 256, 0, stream>>>(t_c2w, t_b2g, wt_t2, 32, 32, 9216);
    prep_b<<<1, 256, 0, stream>>>(nullptr, t_b2g, t_b2b, bt_t2, 32);
    prep_w<<<gsz(5184), 256, 0, stream>>>(e_c1w, e_b1g, wt_c1, 32, 3, 5184);
    prep_b<<<1, 256, 0, stream>>>(e_c1b, e_b1g, e_b1b, bt_c1, 192);
    // MFMA fragment prep: total = E * (CO/16) * 9 * (CI/32) * 512
    prep_wfrag<<<gsz(110592), 256, 0, stream>>>(e_c2w, e_b2g, wfrag_c2, 32, 64, 110592);
    prep_b<<<2, 256, 0, stream>>>(e_c2b, e_b2g, e_b2b, bt_c2, 384);
    prep_wfrag<<<gsz(221184), 256, 0, stream>>>(e_c3w, e_b3g, wfrag_c3, 64, 64, 221184);
    prep_b<<<2, 256, 0, stream>>>(e_c3b, e_b3g, e_b3b, bt_c3, 384);
    prep_wfrag<<<gsz(442368), 256, 0, stream>>>(e_c4w, e_b4g, wfrag_c4, 64, 128, 442368);
    prep_b<<<3, 256, 0, stream>>>(e_c4b, e_b4g, e_b4b, bt_c4, 768);
    prep_wfrag<<<gsz(884736), 256, 0, stream>>>(e_c5w, e_b5g, wfrag_c5, 128, 128, 884736);
    prep_b<<<3, 256, 0, stream>>>(e_c5b, e_b5g, e_b5b, bt_c5, 768);

    // ---- routing trunk (2 batch-halves) ----
    for (int q = 0; q < 2; ++q) {
        const float* xq = x + (size_t)q * 512 * 3 * 1024;
        conv3x3<3, 32, 32, 16, 32, 3, false><<<512 * 4, 256, 0, stream>>>(xq, wt_t1, bt_t1, bufA);
        conv3x3<32, 32, 32, 16, 8, 16, true><<<512 * 4, 256, 0, stream>>>(
            bufA, wt_t2, bt_t2, bufB + (size_t)q * 512 * 32 * 256);
    }
    trunk_pool<<<512, 256, 0, stream>>>(bufB, rf_in);
    fc_k<128, 64, true><<<256, 256, 0, stream>>>(rf_in, t_fcw, t_fcb, rf);
    fc_k<64, 32, true><<<128, 256, 0, stream>>>(rf, g1w, g1b, gv);
    fc_k<32, 6, false><<<24, 256, 0, stream>>>(gv, g2w, g2b, gate);

    // ---- experts ----
    // buffer choreography (per expert iteration):
    //   c1   : x -> bufB            (NCHW fp32 [1024][32][256], 32 MB)
    //   rp16 : bufB -> c2in (bufA)  (packed [1024][256][32], 33.5 MB)
    //   c2/c3 in 2 batch-halves:
    //     c2 : c2in(h) -> bufB      (packed [512][256][64], 32 MB)
    //     c3 : bufB -> c4in(h)      (packed [1024][64][64] at bufA+32MB, 16.8 MB)
    //   c4   : c4in -> bufB         (packed [1024][64][128], 32 MB)
    //   c5   : bufB -> c5out(bufA)  (fp32 [1024][64][128], 33.5 MB; c2in dead)
    unsigned int* c2in  = (unsigned int*)bufA;
    unsigned int* c4in  = (unsigned int*)bufA + 8388608;
    unsigned int* c2out = (unsigned int*)bufB;
    unsigned int* c4out = (unsigned int*)bufB;
    float*        c5out = bufA;
    for (int e = 0; e < E_; ++e) {
        conv3x3<3, 32, 32, 16, 8, 3, true><<<B_ * 4, 256, 0, stream>>>(
            x, wt_c1 + e * 864, bt_c1 + e * 32, bufB);
        repack16<<<B_, 256, 0, stream>>>(bufB, c2in);
        for (int h = 0; h < 2; ++h) {
            conv_mfma16<32, false><<<512, 256, 0, stream>>>(
                c2in + (size_t)h * 512 * 8192, wfrag_c2 + (size_t)e * 36864,
                bt_c2 + e * 64, c2out);
            conv_mfma16<64, true><<<512, 256, 0, stream>>>(
                c2out, wfrag_c3 + (size_t)e * 73728,
                bt_c3 + e * 64, c4in + (size_t)h * 512 * 4096);
        }
        conv_mfma<64, 0><<<512, 256, 0, stream>>>(
            c4in, wfrag_c4 + (size_t)e * 147456, bt_c4 + e * 128, (void*)c4out);
        conv_mfma<128, 1><<<512, 256, 0, stream>>>(
            c4out, wfrag_c5 + (size_t)e * 294912, bt_c5 + e * 128, (void*)c5out);
        gap_nhwc<<<B_, 128, 0, stream>>>(c5out, feat);
        fc_k<128, 128, true><<<512, 256, 0, stream>>>(feat, e_fw + e * 16384, e_fb + e * 128, fv);
        fc_k<128, 10, false><<<40, 256, 0, stream>>>(fv, e_cw + e * 1280, e_cb + e * 10,
                                                     logitsE + (size_t)e * B_ * 10);
    }

    // ---- scoring, dispatch, combine ----
    float* balanced = out + B_ * 10;
    conf_bal_k<<<24, 256, 0, stream>>>(logitsE, gate, ema, balanced);
    dispatch_k<<<1, 64, 0, stream>>>(balanced, chosen);
    final_k<<<4, 256, 0, stream>>>(logitsE, chosen, out);
}

// Round 8
// 2202.657 us; speedup vs baseline: 3.0856x; 1.1092x over previous
//
#include <hip/hip_runtime.h>
#include <math.h>

#define B_ 1024
#define E_ 6

typedef _Float16 half8 __attribute__((ext_vector_type(8)));
typedef float f32x4 __attribute__((ext_vector_type(4)));

__device__ __forceinline__ unsigned short h_bits(_Float16 h) {
    union { _Float16 f; unsigned short u; } c; c.f = h; return c.u;
}
// pack fp32 -> (hi fp16 | lo fp16<<16), lo prescaled by 2048 to avoid fp16 subnormals
__device__ __forceinline__ unsigned int splitpack(float v) {
    _Float16 h = (_Float16)v;
    _Float16 l = (_Float16)((v - (float)h) * 2048.0f);
    return (unsigned int)h_bits(h) | ((unsigned int)h_bits(l) << 16);
}

// ---------------------------------------------------------------------------
// Direct-conv weight prep (t1 + c1): fold BN, transpose to [ci][k][co].
// ---------------------------------------------------------------------------
__global__ void prep_w(const float* __restrict__ w, const float* __restrict__ g,
                       float* __restrict__ wout, int CO, int CI, int total) {
    int i = blockIdx.x * 256 + threadIdx.x;
    if (i >= total) return;
    int k = i % 9;
    int t = i / 9;
    int ci = t % CI; t /= CI;
    int co = t % CO;
    int e  = t / CO;
    float s = g[e * CO + co] * (1.0f / sqrtf(1.0f + 1e-5f));
    wout[(((long)(e * CI + ci) * 9 + k) * CO) + co] = w[i] * s;
}

__global__ void prep_b(const float* __restrict__ cb, const float* __restrict__ g,
                       const float* __restrict__ bb, float* __restrict__ bout, int N) {
    int i = blockIdx.x * 256 + threadIdx.x;
    if (i >= N) return;
    float s = g[i] * (1.0f / sqrtf(1.0f + 1e-5f));
    float c = (cb != nullptr) ? cb[i] : 0.0f;
    bout[i] = c * s + bb[i];
}

// ---------------------------------------------------------------------------
// MFMA weight prep: fold BN, split fp16 hi/lo (lo*2048), B-fragment order
// [e][nbg NB][tap 9][chunk NC][plane 2][lane 64][j 8].
// total = E*NB*9*NC*512 threads; each thread writes BOTH planes
// -> storage per expert = NB*9*NC*1024 f16 (allocate total*2 f16!).
// ---------------------------------------------------------------------------
__global__ void prep_wfrag(const float* __restrict__ w, const float* __restrict__ g,
                           _Float16* __restrict__ out, int CI, int CO, int total) {
    int i = blockIdx.x * 256 + threadIdx.x;
    if (i >= total) return;
    const int NC = CI / 32;
    const int NB = CO / 16;
    int j = i & 7;
    int lane = (i >> 3) & 63;
    int rest = i >> 9;
    int chunk = rest % NC; rest /= NC;
    int tap = rest % 9; rest /= 9;
    int nbg = rest % NB;
    int e = rest / NB;
    int co = nbg * 16 + (lane & 15);
    int ci = chunk * 32 + ((lane >> 4) * 8) + j;
    float s = g[e * CO + co] * (1.0f / sqrtf(1.0f + 1e-5f));
    float v = w[(((long)(e * CO + co) * CI + ci) * 9) + tap] * s;
    _Float16 hi = (_Float16)v;
    _Float16 lo = (_Float16)((v - (float)hi) * 2048.0f);
    long perE = (long)NB * 9 * NC * 2 * 512;
    long F0 = ((long)(nbg * 9 + tap) * NC + chunk) * 2;
    long base = (long)e * perE + F0 * 512 + lane * 8 + j;
    out[base] = hi;
    out[base + 512] = lo;
}

// ---------------------------------------------------------------------------
// Direct conv (t1 + c1).  OUTMODE: 0 = NCHW fp32, 1 = NHWC packed pair dwords.
// ---------------------------------------------------------------------------
template <int CI, int CO, int H, int TS, int CO_BLK, int CI_CHUNK, bool POOL, int OUTMODE>
__launch_bounds__(256)
__global__ void conv3x3(const float* __restrict__ in, const float* __restrict__ wt,
                        const float* __restrict__ bias, void* __restrict__ outv) {
    constexpr int TD = H / TS;
    constexpr int TILES = TD * TD;
    constexpr int LW = TS + 2;
    constexpr int NPX = POOL ? (TS / 2) * (TS / 2) : TS * TS;
    constexpr int G = 256 / NPX;
    constexpr int NG = CO / CO_BLK;
    constexpr int GPT = NG / G;
    constexpr int COT = GPT * CO_BLK;
    constexpr int NW = POOL ? 4 : 1;
    constexpr int OD = POOL ? TS / 2 : TS;

    __shared__ float lds[CI_CHUNK * LW * LW];

    int bid = blockIdx.x;
    int n = bid / TILES;
    int t = bid % TILES;
    int ty = (t / TD) * TS;
    int tx = (t % TD) * TS;
    int tid = threadIdx.x;
    int px = tid % NPX;
    int cg0 = tid / NPX;
    const int cg0s = __builtin_amdgcn_readfirstlane(cg0);
    int oy = px / OD;
    int ox = px % OD;

    float acc[NW][COT];
#pragma unroll
    for (int g2 = 0; g2 < GPT; ++g2)
#pragma unroll
        for (int j = 0; j < CO_BLK; ++j) {
            float bv = bias[(cg0s + g2 * G) * CO_BLK + j];
#pragma unroll
            for (int p = 0; p < NW; ++p) acc[p][g2 * CO_BLK + j] = bv;
        }

    for (int cc = 0; cc < CI / CI_CHUNK; ++cc) {
        const float* inb = in + ((long)n * CI + cc * CI_CHUNK) * (H * H);
        for (int idx = tid; idx < CI_CHUNK * LW * LW; idx += 256) {
            int ci = idx / (LW * LW);
            int r = idx - ci * (LW * LW);
            int yy = r / LW + ty - 1;
            int xx = r % LW + tx - 1;
            float v = 0.0f;
            if ((unsigned)yy < (unsigned)H && (unsigned)xx < (unsigned)H)
                v = inb[ci * H * H + yy * H + xx];
            lds[idx] = v;
        }
        __syncthreads();

        const float* wbase = wt + ((long)cc * CI_CHUNK) * 9 * CO;
        for (int ci = 0; ci < CI_CHUNK; ++ci) {
#pragma unroll
            for (int ky = 0; ky < 3; ++ky) {
#pragma unroll
                for (int kx = 0; kx < 3; ++kx) {
                    float v[NW];
                    if constexpr (POOL) {
#pragma unroll
                        for (int dy = 0; dy < 2; ++dy)
#pragma unroll
                            for (int dx = 0; dx < 2; ++dx)
                                v[dy * 2 + dx] =
                                    lds[ci * LW * LW + (2 * oy + dy + ky) * LW + (2 * ox + dx + kx)];
                    } else {
                        v[0] = lds[ci * LW * LW + (oy + ky) * LW + (ox + kx)];
                    }
                    const float* wr = wbase + ((ci * 3 + ky) * 3 + kx) * CO + cg0s * CO_BLK;
#pragma unroll
                    for (int g2 = 0; g2 < GPT; ++g2)
#pragma unroll
                        for (int j = 0; j < CO_BLK; ++j) {
                            float wv = wr[g2 * G * CO_BLK + j];
#pragma unroll
                            for (int p = 0; p < NW; ++p)
                                acc[p][g2 * CO_BLK + j] = fmaf(v[p], wv, acc[p][g2 * CO_BLK + j]);
                        }
                }
            }
        }
        __syncthreads();
    }

    // epilogue
    if constexpr (OUTMODE == 1) {
        unsigned int* po = (unsigned int*)outv;
        long base;
        if constexpr (POOL) {
            constexpr int HP = H / 2;
            int pp = (ty / 2 + oy) * HP + (tx / 2 + ox);
            base = ((long)n * (HP * HP) + pp) * CO;
        } else {
            int pp = (ty + oy) * H + (tx + ox);
            base = ((long)n * (H * H) + pp) * CO;
        }
#pragma unroll
        for (int g2 = 0; g2 < GPT; ++g2) {
            int cobase = (cg0s + g2 * G) * CO_BLK;
#pragma unroll
            for (int j4 = 0; j4 < CO_BLK; j4 += 4) {
                uint4 u;
                unsigned int* up = (unsigned int*)&u;
#pragma unroll
                for (int jj = 0; jj < 4; ++jj) {
                    int a = g2 * CO_BLK + j4 + jj;
                    float v;
                    if constexpr (POOL)
                        v = fmaxf(fmaxf(acc[0][a], acc[1][a]), fmaxf(acc[2][a], acc[3][a]));
                    else
                        v = acc[0][a];
                    up[jj] = splitpack(fmaxf(v, 0.0f));
                }
                *(uint4*)(po + base + cobase + j4) = u;
            }
        }
    } else {
        float* out = (float*)outv;
        if constexpr (POOL) {
            constexpr int HP = H / 2;
            int py = ty / 2 + oy;
            int pxx = tx / 2 + ox;
#pragma unroll
            for (int g2 = 0; g2 < GPT; ++g2)
#pragma unroll
                for (int j = 0; j < CO_BLK; ++j) {
                    int co = (cg0s + g2 * G) * CO_BLK + j;
                    int a = g2 * CO_BLK + j;
                    float m = fmaxf(fmaxf(acc[0][a], acc[1][a]), fmaxf(acc[2][a], acc[3][a]));
                    out[((long)n * CO + co) * (HP * HP) + py * HP + pxx] = fmaxf(m, 0.0f);
                }
        } else {
            int yy = ty + oy;
            int xx = tx + ox;
#pragma unroll
            for (int g2 = 0; g2 < GPT; ++g2)
#pragma unroll
                for (int j = 0; j < CO_BLK; ++j) {
                    int co = (cg0s + g2 * G) * CO_BLK + j;
                    out[((long)n * CO + co) * (H * H) + yy * H + xx] =
                        fmaxf(acc[0][g2 * CO_BLK + j], 0.0f);
                }
        }
    }
}

// ---------------------------------------------------------------------------
// Trunk t2: MFMA conv 3x3 (32ch->32ch) on a 16x16 tile of a 32x32 image with
// fused 2x2 maxpool AND 8x8 avgpool: each tile reduces to exactly one avgpool
// cell -> block writes 32 floats of rf_in.  Input packed NHWC [n][1024][32].
// ---------------------------------------------------------------------------
__launch_bounds__(256, 2)
__global__ void conv_mfma_t2(const unsigned int* __restrict__ in,
                             const _Float16* __restrict__ wt,
                             const float* __restrict__ bias,
                             float* __restrict__ rf, int n0) {
    constexpr int PXS = 40;
    __shared__ _Float16 ldsH[18 * 18 * PXS];
    __shared__ _Float16 ldsL[18 * 18 * PXS];
    __shared__ float red[4][32];

    const int tid = threadIdx.x;
    const int wv = tid >> 6, lane = tid & 63;
    const int q = lane >> 4, l15 = lane & 15;
    const int bid = blockIdx.x;
    const int nl = bid >> 2, tile = bid & 3;
    const int ty2 = (tile >> 1) * 16, tx2 = (tile & 1) * 16;

    f32x4 accH[8], accL[8];
#pragma unroll
    for (int i = 0; i < 8; ++i) { accH[i] = (f32x4){0,0,0,0}; accL[i] = (f32x4){0,0,0,0}; }

    // stage 18x18 window (halo from neighbors, zero at image edge)
    for (int u = tid; u < 18 * 18 * 8; u += 256) {
        int cu = u & 7;
        int p = u >> 3;
        int wy = p / 18, wx = p % 18;
        int gy = ty2 + wy - 1, gx = tx2 + wx - 1;
        uint4 w = make_uint4(0, 0, 0, 0);
        if ((unsigned)gy < 32u && (unsigned)gx < 32u)
            w = *(const uint4*)(in + ((long)nl * 1024 + gy * 32 + gx) * 32 + cu * 4);
        unsigned int h01 = (w.x & 0xffffu) | (w.y << 16);
        unsigned int h23 = (w.z & 0xffffu) | (w.w << 16);
        unsigned int l01 = (w.x >> 16) | (w.y & 0xffff0000u);
        unsigned int l23 = (w.z >> 16) | (w.w & 0xffff0000u);
        int fi = (wy * 18 + wx) * PXS + cu * 4;
        *(uint2*)(&ldsH[fi]) = make_uint2(h01, h23);
        *(uint2*)(&ldsL[fi]) = make_uint2(l01, l23);
    }
    __syncthreads();

#pragma unroll
    for (int ky = 0; ky < 3; ++ky)
#pragma unroll
        for (int kx = 0; kx < 3; ++kx) {
            const int tap = ky * 3 + kx;
            half8 ah[4], al[4];
#pragma unroll
            for (int mb = 0; mb < 4; ++mb) {
                int y = wv * 4 + mb;
                int fi = ((y + ky) * 18 + (l15 + kx)) * PXS + q * 8;
                ah[mb] = *(const half8*)&ldsH[fi];
                al[mb] = *(const half8*)&ldsL[fi];
            }
            half8 bh[2], bl[2];
#pragma unroll
            for (int nb = 0; nb < 2; ++nb) {
                int F0 = (nb * 9 + tap) * 2;
                bh[nb] = ((const half8*)wt)[(long)F0 * 64 + lane];
                bl[nb] = ((const half8*)wt)[(long)(F0 + 1) * 64 + lane];
            }
#pragma unroll
            for (int nb = 0; nb < 2; ++nb)
#pragma unroll
                for (int mb = 0; mb < 4; ++mb)
                    accH[mb * 2 + nb] = __builtin_amdgcn_mfma_f32_16x16x32_f16(
                        ah[mb], bh[nb], accH[mb * 2 + nb], 0, 0, 0);
#pragma unroll
            for (int nb = 0; nb < 2; ++nb)
#pragma unroll
                for (int mb = 0; mb < 4; ++mb)
                    accL[mb * 2 + nb] = __builtin_amdgcn_mfma_f32_16x16x32_f16(
                        ah[mb], bl[nb], accL[mb * 2 + nb], 0, 0, 0);
#pragma unroll
            for (int nb = 0; nb < 2; ++nb)
#pragma unroll
                for (int mb = 0; mb < 4; ++mb)
                    accL[mb * 2 + nb] = __builtin_amdgcn_mfma_f32_16x16x32_f16(
                        al[mb], bh[nb], accL[mb * 2 + nb], 0, 0, 0);
        }

    // epilogue: relu -> 2x2 maxpool (regs) -> sum for avgpool
    const float inv2048 = 1.0f / 2048.0f;
    float bv[2];
#pragma unroll
    for (int nb = 0; nb < 2; ++nb) bv[nb] = bias[nb * 16 + l15];
    float avg[2] = {0.0f, 0.0f};
#pragma unroll
    for (int k = 0; k < 2; ++k)
#pragma unroll
        for (int j = 0; j < 2; ++j)
#pragma unroll
            for (int nb = 0; nb < 2; ++nb) {
                float m = -1e30f;
#pragma unroll
                for (int dm = 0; dm < 2; ++dm)
#pragma unroll
                    for (int dr = 0; dr < 2; ++dr) {
                        int a = (2 * k + dm) * 2 + nb;
                        int r = 2 * j + dr;
                        float v = accH[a][r] + accL[a][r] * inv2048 + bv[nb];
                        m = fmaxf(m, v);
                    }
                avg[nb] += fmaxf(m, 0.0f);
            }
#pragma unroll
    for (int nb = 0; nb < 2; ++nb) {
        avg[nb] += __shfl_xor(avg[nb], 16);
        avg[nb] += __shfl_xor(avg[nb], 32);
    }
    if (q == 0) {
        red[wv][l15] = avg[0];
        red[wv][16 + l15] = avg[1];
    }
    __syncthreads();
    if (tid < 32) {
        float s = red[0][tid] + red[1][tid] + red[2][tid] + red[3][tid];
        int n = n0 + nl;
        rf[(long)n * 128 + tid * 4 + (tile >> 1) * 2 + (tile & 1)] = s * (1.0f / 64.0f);
    }
}

// ---------------------------------------------------------------------------
// MFMA conv 3x3 on 16x16 spatial, split-fp16, CO=64 (c2 / c3).
// ---------------------------------------------------------------------------
template <int CI, bool POOL>
__launch_bounds__(256, 2)
__global__ void conv_mfma16(const unsigned int* __restrict__ in,
                            const _Float16* __restrict__ wt,
                            const float* __restrict__ bias,
                            unsigned int* __restrict__ outp) {
    constexpr int NC = CI / 32;
    constexpr int PXS = 40;
    __shared__ _Float16 ldsH[18 * 18 * PXS];
    __shared__ _Float16 ldsL[18 * 18 * PXS];

    const int tid = threadIdx.x;
    const int wv = tid >> 6, lane = tid & 63;
    const int q = lane >> 4, l15 = lane & 15;
    const int n = blockIdx.x;

    {
        half8 z = {};
        half8* zh = (half8*)ldsH;
        half8* zl = (half8*)ldsL;
        for (int i = tid; i < 18 * 18 * PXS / 8; i += 256) { zh[i] = z; zl[i] = z; }
    }

    f32x4 accH[16], accL[16];
#pragma unroll
    for (int i = 0; i < 16; ++i) { accH[i] = (f32x4){0,0,0,0}; accL[i] = (f32x4){0,0,0,0}; }

    for (int c = 0; c < NC; ++c) {
        __syncthreads();
        for (int v = tid; v < 2048; v += 256) {
            int cu = v & 7;
            int px = v >> 3;
            long gidx = ((long)n * 256 + px) * CI + c * 32 + cu * 4;
            uint4 w = *(const uint4*)(in + gidx);
            unsigned int h01 = (w.x & 0xffffu) | (w.y << 16);
            unsigned int h23 = (w.z & 0xffffu) | (w.w << 16);
            unsigned int l01 = (w.x >> 16) | (w.y & 0xffff0000u);
            unsigned int l23 = (w.z >> 16) | (w.w & 0xffff0000u);
            int py = px >> 4, pxx = px & 15;
            int fi = ((py + 1) * 18 + (pxx + 1)) * PXS + cu * 4;
            *(uint2*)(&ldsH[fi]) = make_uint2(h01, h23);
            *(uint2*)(&ldsL[fi]) = make_uint2(l01, l23);
        }
        __syncthreads();

#pragma unroll
        for (int ky = 0; ky < 3; ++ky)
#pragma unroll
            for (int kx = 0; kx < 3; ++kx) {
                const int tap = ky * 3 + kx;
                half8 ah[4], al[4];
#pragma unroll
                for (int mb = 0; mb < 4; ++mb) {
                    int y = wv * 4 + mb;
                    int fi = ((y + ky) * 18 + (l15 + kx)) * PXS + q * 8;
                    ah[mb] = *(const half8*)&ldsH[fi];
                    al[mb] = *(const half8*)&ldsL[fi];
                }
                half8 bh[4], bl[4];
#pragma unroll
                for (int nb = 0; nb < 4; ++nb) {
                    int F0 = ((nb * 9 + tap) * NC + c) * 2;
                    bh[nb] = ((const half8*)wt)[(long)F0 * 64 + lane];
                    bl[nb] = ((const half8*)wt)[(long)(F0 + 1) * 64 + lane];
                }
#pragma unroll
                for (int nb = 0; nb < 4; ++nb)
#pragma unroll
                    for (int mb = 0; mb < 4; ++mb)
                        accH[mb * 4 + nb] = __builtin_amdgcn_mfma_f32_16x16x32_f16(
                            ah[mb], bh[nb], accH[mb * 4 + nb], 0, 0, 0);
#pragma unroll
                for (int nb = 0; nb < 4; ++nb)
#pragma unroll
                    for (int mb = 0; mb < 4; ++mb)
                        accL[mb * 4 + nb] = __builtin_amdgcn_mfma_f32_16x16x32_f16(
                            ah[mb], bl[nb], accL[mb * 4 + nb], 0, 0, 0);
#pragma unroll
                for (int nb = 0; nb < 4; ++nb)
#pragma unroll
                    for (int mb = 0; mb < 4; ++mb)
                        accL[mb * 4 + nb] = __builtin_amdgcn_mfma_f32_16x16x32_f16(
                            al[mb], bh[nb], accL[mb * 4 + nb], 0, 0, 0);
            }
    }

    const float inv2048 = 1.0f / 2048.0f;
    float bv[4];
#pragma unroll
    for (int nb = 0; nb < 4; ++nb) bv[nb] = bias[nb * 16 + l15];

    if constexpr (POOL) {
#pragma unroll
        for (int k = 0; k < 2; ++k) {
#pragma unroll
            for (int j = 0; j < 2; ++j) {
                int yy = wv * 2 + k;
                int xx = q * 2 + j;
                long base = ((long)n * 64 + yy * 8 + xx) * 64;
#pragma unroll
                for (int nb = 0; nb < 4; ++nb) {
                    float m = -1e30f;
#pragma unroll
                    for (int dm = 0; dm < 2; ++dm)
#pragma unroll
                        for (int dr = 0; dr < 2; ++dr) {
                            int a = (2 * k + dm) * 4 + nb;
                            int r = 2 * j + dr;
                            float v = accH[a][r] + accL[a][r] * inv2048 + bv[nb];
                            m = fmaxf(m, v);
                        }
                    m = fmaxf(m, 0.0f);
                    outp[base + nb * 16 + l15] = splitpack(m);
                }
            }
        }
    } else {
#pragma unroll
        for (int mb = 0; mb < 4; ++mb) {
            int y = wv * 4 + mb;
#pragma unroll
            for (int r = 0; r < 4; ++r) {
                int px = y * 16 + q * 4 + r;
                long base = ((long)n * 256 + px) * 64;
#pragma unroll
                for (int nb = 0; nb < 4; ++nb) {
                    float v = accH[mb * 4 + nb][r] + accL[mb * 4 + nb][r] * inv2048 + bv[nb];
                    v = fmaxf(v, 0.0f);
                    outp[base + nb * 16 + l15] = splitpack(v);
                }
            }
        }
    }
}

// ---------------------------------------------------------------------------
// MFMA conv 3x3 on 8x8 spatial (c4/c5), split-fp16, CO=128.  2 images/block.
// ---------------------------------------------------------------------------
template <int CI, int OUTF32>
__launch_bounds__(256, 2)
__global__ void conv_mfma(const unsigned int* __restrict__ in,
                          const _Float16* __restrict__ wt,
                          const float* __restrict__ bias, void* __restrict__ outv) {
    constexpr int NC = CI / 32;
    constexpr int PXS = 40;
    __shared__ _Float16 ldsH[2 * 100 * PXS];
    __shared__ _Float16 ldsL[2 * 100 * PXS];

    const int tid = threadIdx.x;
    const int wv = tid >> 6, lane = tid & 63;
    const int ph = wv & 1, ch = wv >> 1;
    const int q = lane >> 4, l15 = lane & 15;
    const int n0 = blockIdx.x * 2;

    {
        half8 z = {};
        half8* zh = (half8*)ldsH;
        half8* zl = (half8*)ldsL;
        for (int i = tid; i < 2 * 100 * PXS / 8; i += 256) { zh[i] = z; zl[i] = z; }
    }

    f32x4 accH[16], accL[16];
#pragma unroll
    for (int i = 0; i < 16; ++i) { accH[i] = (f32x4){0,0,0,0}; accL[i] = (f32x4){0,0,0,0}; }

    for (int c = 0; c < NC; ++c) {
        __syncthreads();
        for (int u = tid; u < 1024; u += 256) {
            int cu = u & 7;
            int px = (u >> 3) & 63;
            int img = u >> 9;
            long gidx = ((long)(n0 + img) * 64 + px) * CI + c * 32 + cu * 4;
            uint4 w = *(const uint4*)(in + gidx);
            unsigned int h01 = (w.x & 0xffffu) | (w.y << 16);
            unsigned int h23 = (w.z & 0xffffu) | (w.w << 16);
            unsigned int l01 = (w.x >> 16) | (w.y & 0xffff0000u);
            unsigned int l23 = (w.z >> 16) | (w.w & 0xffff0000u);
            int py = px >> 3, pxx = px & 7;
            int fi = (img * 100 + (py + 1) * 10 + (pxx + 1)) * PXS + cu * 4;
            *(uint2*)(&ldsH[fi]) = make_uint2(h01, h23);
            *(uint2*)(&ldsL[fi]) = make_uint2(l01, l23);
        }
        __syncthreads();

#pragma unroll
        for (int ky = 0; ky < 3; ++ky)
#pragma unroll
            for (int kx = 0; kx < 3; ++kx) {
                const int tap = ky * 3 + kx;
                half8 ah[4], al[4];
#pragma unroll
                for (int mb = 0; mb < 4; ++mb) {
                    int m = ph * 64 + mb * 16 + l15;
                    int img = m >> 6, py = (m >> 3) & 7, pxx = m & 7;
                    int fi = (img * 100 + (py + ky) * 10 + (pxx + kx)) * PXS + q * 8;
                    ah[mb] = *(const half8*)&ldsH[fi];
                    al[mb] = *(const half8*)&ldsL[fi];
                }
                half8 bh[4], bl[4];
#pragma unroll
                for (int nb = 0; nb < 4; ++nb) {
                    int nbg = ch * 4 + nb;
                    int F0 = ((nbg * 9 + tap) * NC + c) * 2;
                    bh[nb] = ((const half8*)wt)[(long)F0 * 64 + lane];
                    bl[nb] = ((const half8*)wt)[(long)(F0 + 1) * 64 + lane];
                }
#pragma unroll
                for (int nb = 0; nb < 4; ++nb)
#pragma unroll
                    for (int mb = 0; mb < 4; ++mb)
                        accH[mb * 4 + nb] = __builtin_amdgcn_mfma_f32_16x16x32_f16(
                            ah[mb], bh[nb], accH[mb * 4 + nb], 0, 0, 0);
#pragma unroll
                for (int nb = 0; nb < 4; ++nb)
#pragma unroll
                    for (int mb = 0; mb < 4; ++mb)
                        accL[mb * 4 + nb] = __builtin_amdgcn_mfma_f32_16x16x32_f16(
                            ah[mb], bl[nb], accL[mb * 4 + nb], 0, 0, 0);
#pragma unroll
                for (int nb = 0; nb < 4; ++nb)
#pragma unroll
                    for (int mb = 0; mb < 4; ++mb)
                        accL[mb * 4 + nb] = __builtin_amdgcn_mfma_f32_16x16x32_f16(
                            al[mb], bh[nb], accL[mb * 4 + nb], 0, 0, 0);
            }
    }

    const float inv2048 = 1.0f / 2048.0f;
    float bv[4];
#pragma unroll
    for (int nb = 0; nb < 4; ++nb) bv[nb] = bias[ch * 64 + nb * 16 + l15];
#pragma unroll
    for (int mb = 0; mb < 4; ++mb) {
#pragma unroll
        for (int r = 0; r < 4; ++r) {
            int m = ph * 64 + mb * 16 + q * 4 + r;
            int img = m >> 6, px = m & 63;
            long base = ((long)(n0 + img) * 64 + px) * 128;
#pragma unroll
            for (int nb = 0; nb < 4; ++nb) {
                float v = accH[mb * 4 + nb][r] + accL[mb * 4 + nb][r] * inv2048 + bv[nb];
                v = fmaxf(v, 0.0f);
                int co = ch * 64 + nb * 16 + l15;
                if constexpr (OUTF32) {
                    ((float*)outv)[base + co] = v;
                } else {
                    ((unsigned int*)outv)[base + co] = splitpack(v);
                }
            }
        }
    }
}

// ---------------------------------------------------------------------------
// Fused expert head: GAP (NHWC fp32 [n][64][128]) -> fc1(128,relu) -> fc2(10).
// ---------------------------------------------------------------------------
__launch_bounds__(128)
__global__ void head_k(const float* __restrict__ in, const float* __restrict__ fw,
                       const float* __restrict__ fb, const float* __restrict__ cw,
                       const float* __restrict__ cb, float* __restrict__ outl) {
    __shared__ float feat[128];
    __shared__ float fv[128];
    int n = blockIdx.x, t = threadIdx.x;
    const float* p = in + (long)n * 8192 + t;
    float s = 0.0f;
#pragma unroll
    for (int px = 0; px < 64; ++px) s += p[px * 128];
    feat[t] = s * (1.0f / 64.0f);
    __syncthreads();
    const float* wr = fw + t * 128;
    float a = fb[t];
#pragma unroll 8
    for (int k = 0; k < 128; ++k) a = fmaf(feat[k], wr[k], a);
    fv[t] = fmaxf(a, 0.0f);
    __syncthreads();
    if (t < 10) {
        const float* cr = cw + t * 128;
        float a2 = cb[t];
#pragma unroll 8
        for (int k = 0; k < 128; ++k) a2 = fmaf(fv[k], cr[k], a2);
        outl[n * 10 + t] = a2;
    }
}

// FC (trunk)
template <int I, int O, bool RELU>
__global__ void fc_k(const float* __restrict__ in, const float* __restrict__ W,
                     const float* __restrict__ bias, float* __restrict__ out) {
    int g = blockIdx.x * 256 + threadIdx.x;
    if (g >= B_ * O) return;
    int n = g / O;
    int o = g - n * O;
    const float* ip = in + (long)n * I;
    const float* wp = W + (long)o * I;
    float a = bias[o];
#pragma unroll 8
    for (int k = 0; k < I; ++k) a = fmaf(ip[k], wp[k], a);
    if (RELU) a = fmaxf(a, 0.0f);
    out[g] = a;
}

// ---------------------------------------------------------------------------
// conf + balanced + top-2 candidates (one thread per sample).
// ---------------------------------------------------------------------------
__global__ void conf_bal_k(const float* __restrict__ logitsE, const float* __restrict__ gate,
                           const float* __restrict__ ema, float* __restrict__ balanced,
                           unsigned char* __restrict__ cand) {
    int b = blockIdx.x * 256 + threadIdx.x;
    if (b >= B_) return;
    float bal[E_];
#pragma unroll
    for (int e = 0; e < E_; ++e) {
        const float* lp = logitsE + ((long)e * B_ + b) * 10;
        float m = lp[0];
#pragma unroll
        for (int k = 1; k < 10; ++k) m = fmaxf(m, lp[k]);
        float s = 0.0f;
#pragma unroll
        for (int k = 0; k < 10; ++k) s += expf(lp[k] - m);
        float ls = m + logf(s);
        float conf = 0.0f;
#pragma unroll
        for (int k = 0; k < 10; ++k) {
            float pp = expf(lp[k] - ls);
            conf += pp * logf(pp + 1e-12f);
        }
        float em = ema[e];
        float boost = (em < 0.05f) ? (0.05f - em) * 10.0f : 0.0f;
        bal[e] = 0.7f * gate[b * E_ + e] + 0.3f * conf + boost - 2.0f * em;
        balanced[b * E_ + e] = bal[e];
    }
    int i0 = 0;
    float m0 = bal[0];
#pragma unroll
    for (int e = 1; e < E_; ++e)
        if (bal[e] > m0) { m0 = bal[e]; i0 = e; }
    int i1 = -1;
    float m1 = -1e38f;
#pragma unroll
    for (int e = 0; e < E_; ++e)
        if (e != i0 && bal[e] > m1) { m1 = bal[e]; i1 = e; }
    cand[b] = (unsigned char)(i0 | (i1 << 3));
}

// ---------------------------------------------------------------------------
// Sequential greedy capacity dispatch — scalarized (SALU loads state; readlane
// broadcasts candidates).  Exact replica of the reference scan semantics.
// ---------------------------------------------------------------------------
__global__ void dispatch_k(const unsigned char* __restrict__ cand, int* __restrict__ chosen) {
    int lane = threadIdx.x;
    unsigned long long L = 0;
    for (int r = 0; r < 16; ++r) {
        unsigned int v = cand[r * 64 + lane];
        int ch = 0;
        for (int q2 = 0; q2 < 64; ++q2) {
            unsigned int s = (unsigned int)__builtin_amdgcn_readlane((int)v, q2);
            unsigned int i0 = s & 7u;
            unsigned int i1 = (s >> 3) & 7u;
            unsigned int a0 = (unsigned int)(L >> (i0 * 10)) & 1023u;
            unsigned int a1 = (unsigned int)(L >> (i1 * 10)) & 1023u;
            unsigned int fb = (a1 < a0) ? i1 : i0;
            unsigned int c = (a0 < 192u) ? i0 : ((a1 < 192u) ? i1 : fb);
            if (lane == q2) ch = (int)c;
            L += 1ull << (c * 10);
        }
        chosen[r * 64 + lane] = ch;
    }
}

__global__ void final_k(const float* __restrict__ logitsE, const int* __restrict__ chosen,
                        float* __restrict__ out) {
    int b = blockIdx.x * 256 + threadIdx.x;
    if (b >= B_) return;
    int c = chosen[b];
    const float w = 1.0f / (1.0f + 1e-12f);
    const float* lp = logitsE + ((long)c * B_ + b) * 10;
#pragma unroll
    for (int k = 0; k < 10; ++k) out[b * 10 + k] = lp[k] * w;
    float* Dp = out + B_ * 10 + B_ * E_ + b * E_;
#pragma unroll
    for (int e = 0; e < E_; ++e) Dp[e] = (e == c) ? 1.0f : 0.0f;
}

// ---------------------------------------------------------------------------
extern "C" void kernel_launch(void* const* d_in, const int* in_sizes, int n_in,
                              void* d_out, int out_size, void* d_ws, size_t ws_size,
                              hipStream_t stream) {
    (void)in_sizes; (void)n_in; (void)out_size; (void)ws_size;
    const float* x     = (const float*)d_in[0];
    const float* t_c1w = (const float*)d_in[1];
    const float* t_b1g = (const float*)d_in[2];
    const float* t_b1b = (const float*)d_in[3];
    const float* t_c2w = (const float*)d_in[4];
    const float* t_b2g = (const float*)d_in[5];
    const float* t_b2b = (const float*)d_in[6];
    const float* t_fcw = (const float*)d_in[7];
    const float* t_fcb = (const float*)d_in[8];
    const float* g1w   = (const float*)d_in[9];
    const float* g1b   = (const float*)d_in[10];
    const float* g2w   = (const float*)d_in[11];
    const float* g2b   = (const float*)d_in[12];
    const float* e_c1w = (const float*)d_in[13];
    const float* e_c1b = (const float*)d_in[14];
    const float* e_b1g = (const float*)d_in[15];
    const float* e_b1b = (const float*)d_in[16];
    const float* e_c2w = (const float*)d_in[17];
    const float* e_c2b = (const float*)d_in[18];
    const float* e_b2g = (const float*)d_in[19];
    const float* e_b2b = (const float*)d_in[20];
    const float* e_c3w = (const float*)d_in[21];
    const float* e_c3b = (const float*)d_in[22];
    const float* e_b3g = (const float*)d_in[23];
    const float* e_b3b = (const float*)d_in[24];
    const float* e_c4w = (const float*)d_in[25];
    const float* e_c4b = (const float*)d_in[26];
    const float* e_b4g = (const float*)d_in[27];
    const float* e_b4b = (const float*)d_in[28];
    const float* e_c5w = (const float*)d_in[29];
    const float* e_c5b = (const float*)d_in[30];
    const float* e_b5g = (const float*)d_in[31];
    const float* e_b5b = (const float*)d_in[32];
    const float* e_fw  = (const float*)d_in[33];
    const float* e_fb  = (const float*)d_in[34];
    const float* e_cw  = (const float*)d_in[35];
    const float* e_cb  = (const float*)d_in[36];
    const float* ema   = (const float*)d_in[37];
    float* out = (float*)d_out;
    float* ws  = (float*)d_ws;

    // workspace layout — ALL offsets in FLOAT units.
    // fragment arrays: f16 count = threads*2 -> float slots = threads.
    size_t o = 0;
    float* R1f = ws + o; o += 8388608;    // 32 MB ping
    float* R2f = ws + o; o += 16777216;   // 64 MB pong
    float* rf_in   = ws + o; o += B_ * 128;
    float* rf      = ws + o; o += B_ * 64;
    float* gv      = ws + o; o += B_ * 32;
    float* gate    = ws + o; o += B_ * E_;
    float* logitsE = ws + o; o += E_ * B_ * 10;
    int*   chosen  = (int*)(ws + o); o += B_;
    unsigned char* cand = (unsigned char*)(ws + o); o += 256;
    // small bias/weight tables FIRST so fragment arrays are last
    float* wt_t1 = ws + o; o += 864;
    float* bt_t1 = ws + o; o += 32;
    float* bt_t2 = ws + o; o += 32;
    float* wt_c1 = ws + o; o += 6 * 864;
    float* bt_c1 = ws + o; o += 6 * 32;
    float* bt_c2 = ws + o; o += 6 * 64;
    float* bt_c3 = ws + o; o += 6 * 64;
    float* bt_c4 = ws + o; o += 6 * 128;
    float* bt_c5 = ws + o; o += 6 * 128;
    _Float16* wfrag_t2 = (_Float16*)(ws + o); o += 9216;     // 18432 f16 = 1*(2*9*1*1024)
    _Float16* wfrag_c2 = (_Float16*)(ws + o); o += 110592;   // 221184 f16 = 6*36864
    _Float16* wfrag_c3 = (_Float16*)(ws + o); o += 221184;   // 442368 f16 = 6*73728
    _Float16* wfrag_c4 = (_Float16*)(ws + o); o += 442368;   // 884736 f16 = 6*147456
    _Float16* wfrag_c5 = (_Float16*)(ws + o); o += 884736;   // 1769472 f16 = 6*294912

    unsigned int* R1u = (unsigned int*)R1f;
    unsigned int* R2u = (unsigned int*)R2f;

    auto gsz = [](int n) { return (n + 255) / 256; };
    // ---- weight prep ----
    prep_w<<<gsz(864), 256, 0, stream>>>(t_c1w, t_b1g, wt_t1, 32, 3, 864);
    prep_b<<<1, 256, 0, stream>>>(nullptr, t_b1g, t_b1b, bt_t1, 32);
    prep_wfrag<<<gsz(9216), 256, 0, stream>>>(t_c2w, t_b2g, wfrag_t2, 32, 32, 9216);
    prep_b<<<1, 256, 0, stream>>>(nullptr, t_b2g, t_b2b, bt_t2, 32);
    prep_w<<<gsz(5184), 256, 0, stream>>>(e_c1w, e_b1g, wt_c1, 32, 3, 5184);
    prep_b<<<1, 256, 0, stream>>>(e_c1b, e_b1g, e_b1b, bt_c1, 192);
    prep_wfrag<<<gsz(110592), 256, 0, stream>>>(e_c2w, e_b2g, wfrag_c2, 32, 64, 110592);
    prep_b<<<2, 256, 0, stream>>>(e_c2b, e_b2g, e_b2b, bt_c2, 384);
    prep_wfrag<<<gsz(221184), 256, 0, stream>>>(e_c3w, e_b3g, wfrag_c3, 64, 64, 221184);
    prep_b<<<2, 256, 0, stream>>>(e_c3b, e_b3g, e_b3b, bt_c3, 384);
    prep_wfrag<<<gsz(442368), 256, 0, stream>>>(e_c4w, e_b4g, wfrag_c4, 64, 128, 442368);
    prep_b<<<3, 256, 0, stream>>>(e_c4b, e_b4g, e_b4b, bt_c4, 768);
    prep_wfrag<<<gsz(884736), 256, 0, stream>>>(e_c5w, e_b5g, wfrag_c5, 128, 128, 884736);
    prep_b<<<3, 256, 0, stream>>>(e_c5b, e_b5g, e_b5b, bt_c5, 768);

    // ---- routing trunk (2 batch-halves; t1 -> packed NHWC in R2) ----
    for (int q = 0; q < 2; ++q) {
        const float* xq = x + (size_t)q * 512 * 3 * 1024;
        conv3x3<3, 32, 32, 16, 32, 3, false, 1><<<512 * 4, 256, 0, stream>>>(
            xq, wt_t1, bt_t1, (void*)R2u);
        conv_mfma_t2<<<512 * 4, 256, 0, stream>>>(R2u, wfrag_t2, bt_t2, rf_in, q * 512);
    }
    fc_k<128, 64, true><<<256, 256, 0, stream>>>(rf_in, t_fcw, t_fcb, rf);
    fc_k<64, 32, true><<<128, 256, 0, stream>>>(rf, g1w, g1b, gv);
    fc_k<32, 6, false><<<24, 256, 0, stream>>>(gv, g2w, g2b, gate);

    // ---- experts ----
    // c1: x -> R1 (packed [1024][256][32], 32 MB)
    // c2: R1 -> R2 (packed [1024][256][64], 64 MB)
    // c3: R2 -> R1 (packed [1024][64][64], 16 MB)
    // c4: R1 -> R2 (packed [1024][64][128], 32 MB)
    // c5: R2 -> R1 (fp32 [1024][64][128], 32 MB)
    for (int e = 0; e < E_; ++e) {
        conv3x3<3, 32, 32, 16, 8, 3, true, 1><<<B_ * 4, 256, 0, stream>>>(
            x, wt_c1 + e * 864, bt_c1 + e * 32, (void*)R1u);
        conv_mfma16<32, false><<<B_, 256, 0, stream>>>(
            R1u, wfrag_c2 + (size_t)e * 36864, bt_c2 + e * 64, R2u);
        conv_mfma16<64, true><<<B_, 256, 0, stream>>>(
            R2u, wfrag_c3 + (size_t)e * 73728, bt_c3 + e * 64, R1u);
        conv_mfma<64, 0><<<512, 256, 0, stream>>>(
            R1u, wfrag_c4 + (size_t)e * 147456, bt_c4 + e * 128, (void*)R2u);
        conv_mfma<128, 1><<<512, 256, 0, stream>>>(
            R2u, wfrag_c5 + (size_t)e * 294912, bt_c5 + e * 128, (void*)R1f);
        head_k<<<B_, 128, 0, stream>>>(R1f, e_fw + e * 16384, e_fb + e * 128,
                                       e_cw + e * 1280, e_cb + e * 10,
                                       logitsE + (size_t)e * B_ * 10);
    }

    // ---- scoring, dispatch, combine ----
    float* balanced = out + B_ * 10;
    conf_bal_k<<<4, 256, 0, stream>>>(logitsE, gate, ema, balanced, cand);
    dispatch_k<<<1, 64, 0, stream>>>(cand, chosen);
    final_k<<<4, 256, 0, stream>>>(logitsE, chosen, out);
}